// Round 1
// baseline (708.259 us; speedup 1.0000x reference)
//
#include <hip/hip_runtime.h>

#define N_NODES 100000
#define N_EDGES 3200000
#define F_IN    61
#define F_HID   16
#define F_OUT   2

// ---------------- Kernel A: layer-1 node transforms ----------------
// y = x @ [W1[0] | W1[1] | root1]; writes hp[n][c] = {h0,h1} interleaved,
// r1[n][c] = x@root1 + b1.
__global__ __launch_bounds__(128) void k_transform1(
    const float* __restrict__ x, const float* __restrict__ W1,
    const float* __restrict__ root1, const float* __restrict__ b1,
    float2* __restrict__ hp, float* __restrict__ r1)
{
    __shared__ float xs[128 * F_IN];          // 31.2 KB
    __shared__ float w0s[F_IN * F_HID];       // 3.9 KB
    __shared__ float w1s[F_IN * F_HID];
    __shared__ float rs [F_IN * F_HID];
    __shared__ float bs [F_HID];

    const int tid = threadIdx.x;
    for (int i = tid; i < F_IN * F_HID; i += 128) {
        w0s[i] = W1[i];
        w1s[i] = W1[F_IN * F_HID + i];
        rs[i]  = root1[i];
    }
    if (tid < F_HID) bs[tid] = b1[tid];

    const int n0 = blockIdx.x * 128;
    const int nodes = min(128, N_NODES - n0);
    for (int i = tid; i < nodes * F_IN; i += 128)
        xs[i] = x[(size_t)n0 * F_IN + i];
    __syncthreads();

    if (tid < nodes) {
        const int n = n0 + tid;
        float a0[F_HID], a1[F_HID], ar[F_HID];
        #pragma unroll
        for (int c = 0; c < F_HID; ++c) { a0[c] = 0.f; a1[c] = 0.f; ar[c] = 0.f; }
        const float* xr = &xs[tid * F_IN];
        for (int f = 0; f < F_IN; ++f) {
            const float xv = xr[f];
            #pragma unroll
            for (int c = 0; c < F_HID; ++c) {
                a0[c] = fmaf(xv, w0s[f * F_HID + c], a0[c]);
                a1[c] = fmaf(xv, w1s[f * F_HID + c], a1[c]);
                ar[c] = fmaf(xv, rs [f * F_HID + c], ar[c]);
            }
        }
        #pragma unroll
        for (int c = 0; c < F_HID; ++c) {
            hp[(size_t)n * F_HID + c] = make_float2(a0[c], a1[c]);
            r1[(size_t)n * F_HID + c] = ar[c] + bs[c];
        }
    }
}

// ---------------- Kernel B: layer-1 edge scatter (16 lanes / edge) ---------
__global__ __launch_bounds__(256) void k_edge1(
    const int* __restrict__ esrc, const int* __restrict__ edst,
    const float* __restrict__ attr, const float2* __restrict__ hp,
    float* __restrict__ sum1, float* __restrict__ cnt)
{
    const int gtid   = blockIdx.x * blockDim.x + threadIdx.x;
    const int stride = gridDim.x * blockDim.x;
    const int j      = gtid & (F_HID - 1);
    const int estep  = stride >> 4;
    for (int e = gtid >> 4; e < N_EDGES; e += estep) {
        const int   s = esrc[e];
        const int   d = edst[e];
        const float u = attr[e];
        const float2 h = hp[(size_t)s * F_HID + j];
        const float  m = (1.0f - u) * h.x + u * h.y;
        atomicAdd(&sum1[(size_t)d * F_HID + j], m);
        if (j == 0) atomicAdd(&cnt[d], 1.0f);
    }
}

// ---------------- Kernel C: finalize layer 1 + layer-2 node transforms -----
__global__ __launch_bounds__(256) void k_mid(
    const float* __restrict__ sum1, const float* __restrict__ cnt,
    const float* __restrict__ r1,
    const float* __restrict__ W2, const float* __restrict__ root2,
    const float* __restrict__ b2,
    float4* __restrict__ h2, float2* __restrict__ r2)
{
    __shared__ float w2s[2 * F_HID * F_OUT];  // 64
    __shared__ float rts[F_HID * F_OUT];      // 32
    __shared__ float b2s[F_OUT];
    const int tid = threadIdx.x;
    if (tid < 2 * F_HID * F_OUT) w2s[tid] = W2[tid];
    if (tid < F_HID * F_OUT)     rts[tid] = root2[tid];
    if (tid < F_OUT)             b2s[tid] = b2[tid];
    __syncthreads();

    const int gtid   = blockIdx.x * blockDim.x + tid;
    const int stride = gridDim.x * blockDim.x;
    for (int n = gtid; n < N_NODES; n += stride) {
        const float inv = 1.0f / fmaxf(cnt[n], 1.0f);
        float h[F_HID];
        #pragma unroll
        for (int c = 0; c < F_HID; ++c) {
            const float v = sum1[(size_t)n * F_HID + c] * inv + r1[(size_t)n * F_HID + c];
            h[c] = (v > 0.0f) ? v : expm1f(v);   // ELU, alpha=1
        }
        float o00 = 0.f, o01 = 0.f, o10 = 0.f, o11 = 0.f;
        float rr0 = b2s[0], rr1 = b2s[1];
        #pragma unroll
        for (int f = 0; f < F_HID; ++f) {
            o00 = fmaf(h[f], w2s[f * 2 + 0], o00);
            o01 = fmaf(h[f], w2s[f * 2 + 1], o01);
            o10 = fmaf(h[f], w2s[2 * F_HID + f * 2 + 0], o10);
            o11 = fmaf(h[f], w2s[2 * F_HID + f * 2 + 1], o11);
            rr0 = fmaf(h[f], rts[f * 2 + 0], rr0);
            rr1 = fmaf(h[f], rts[f * 2 + 1], rr1);
        }
        h2[n] = make_float4(o00, o01, o10, o11);
        r2[n] = make_float2(rr0, rr1);
    }
}

// ---------------- Kernel D: layer-2 edge scatter (1 thread / edge) ---------
__global__ __launch_bounds__(256) void k_edge2(
    const int* __restrict__ esrc, const int* __restrict__ edst,
    const float* __restrict__ attr, const float4* __restrict__ h2,
    float* __restrict__ sum2)
{
    const int gtid   = blockIdx.x * blockDim.x + threadIdx.x;
    const int stride = gridDim.x * blockDim.x;
    for (int e = gtid; e < N_EDGES; e += stride) {
        const int   s = esrc[e];
        const int   d = edst[e];
        const float u = attr[e];
        const float4 h = h2[s];
        const float w0 = 1.0f - u;
        atomicAdd(&sum2[(size_t)d * 2 + 0], w0 * h.x + u * h.z);
        atomicAdd(&sum2[(size_t)d * 2 + 1], w0 * h.y + u * h.w);
    }
}

// ---------------- Kernel E: finalize layer 2 + log_softmax ----------------
__global__ __launch_bounds__(256) void k_final(
    const float* __restrict__ sum2, const float* __restrict__ cnt,
    const float2* __restrict__ r2, float2* __restrict__ out)
{
    const int gtid   = blockIdx.x * blockDim.x + threadIdx.x;
    const int stride = gridDim.x * blockDim.x;
    for (int n = gtid; n < N_NODES; n += stride) {
        const float inv = 1.0f / fmaxf(cnt[n], 1.0f);
        const float2 r = r2[n];
        const float o0 = sum2[(size_t)n * 2 + 0] * inv + r.x;
        const float o1 = sum2[(size_t)n * 2 + 1] * inv + r.y;
        const float m  = fmaxf(o0, o1);
        const float l  = m + logf(expf(o0 - m) + expf(o1 - m));
        out[n] = make_float2(o0 - l, o1 - l);
    }
}

extern "C" void kernel_launch(void* const* d_in, const int* in_sizes, int n_in,
                              void* d_out, int out_size, void* d_ws, size_t ws_size,
                              hipStream_t stream) {
    const float* x     = (const float*)d_in[0];
    const int*   ei    = (const int*)  d_in[1];   // [2][N_EDGES]
    const float* attr  = (const float*)d_in[2];
    // d_in[3] = dropout (0) — ignored
    const float* W1    = (const float*)d_in[4];
    const float* root1 = (const float*)d_in[5];
    const float* b1    = (const float*)d_in[6];
    const float* W2    = (const float*)d_in[7];
    const float* root2 = (const float*)d_in[8];
    const float* b2    = (const float*)d_in[9];
    float2* out = (float2*)d_out;

    char* ws = (char*)d_ws;
    size_t off = 0;
    float2* hp   = (float2*)(ws + off); off += (size_t)N_NODES * F_HID * sizeof(float2); // 12.8MB
    float*  r1   = (float*) (ws + off); off += (size_t)N_NODES * F_HID * sizeof(float);  // 6.4MB
    float4* h2   = (float4*)(ws + off); off += (size_t)N_NODES * sizeof(float4);         // 1.6MB
    float2* r2   = (float2*)(ws + off); off += (size_t)N_NODES * sizeof(float2);         // 0.8MB
    // accumulators kept contiguous so one memset clears all three
    float*  sum1 = (float*) (ws + off); off += (size_t)N_NODES * F_HID * sizeof(float);  // 6.4MB
    float*  cnt  = (float*) (ws + off); off += (size_t)N_NODES * sizeof(float);          // 0.4MB
    float*  sum2 = (float*) (ws + off); off += (size_t)N_NODES * 2 * sizeof(float);      // 0.8MB

    const size_t accum_bytes = (size_t)N_NODES * (F_HID + 1 + 2) * sizeof(float);
    hipMemsetAsync(sum1, 0, accum_bytes, stream);

    const int* esrc = ei;
    const int* edst = ei + N_EDGES;

    k_transform1<<<(N_NODES + 127) / 128, 128, 0, stream>>>(x, W1, root1, b1, hp, r1);
    k_edge1<<<2048, 256, 0, stream>>>(esrc, edst, attr, hp, sum1, cnt);
    k_mid<<<512, 256, 0, stream>>>(sum1, cnt, r1, W2, root2, b2, h2, r2);
    k_edge2<<<2048, 256, 0, stream>>>(esrc, edst, attr, h2, sum2);
    k_final<<<256, 256, 0, stream>>>(sum2, cnt, r2, out);
}

// Round 2
// 448.181 us; speedup vs baseline: 1.5803x; 1.5803x over previous
//
#include <hip/hip_runtime.h>
#include <hip/hip_fp16.h>

#define N_NODES 100000
#define N_EDGES 3200000
#define F_IN    61
#define F_HID   16
#define F_OUT   2
#define HB      64       // histogram partial rows (grid.x)
#define HRANGE  50000    // histogram bins per pass (grid.y = 2 passes)

// ---------------- Kernel A: layer-1 node transforms ----------------
// hp[n][c] = half2(h0[c], h1[c]);  r1[n][c] = (x @ root1 + b1)[c]  (f32)
__global__ __launch_bounds__(128) void k_transform1(
    const float* __restrict__ x, const float* __restrict__ W1,
    const float* __restrict__ root1, const float* __restrict__ b1,
    __half2* __restrict__ hp, float* __restrict__ r1)
{
    __shared__ float xs[128 * F_IN];
    __shared__ float w0s[F_IN * F_HID];
    __shared__ float w1s[F_IN * F_HID];
    __shared__ float rs [F_IN * F_HID];
    __shared__ float bs [F_HID];

    const int tid = threadIdx.x;
    for (int i = tid; i < F_IN * F_HID; i += 128) {
        w0s[i] = W1[i];
        w1s[i] = W1[F_IN * F_HID + i];
        rs[i]  = root1[i];
    }
    if (tid < F_HID) bs[tid] = b1[tid];

    const int n0 = blockIdx.x * 128;
    const int nodes = min(128, N_NODES - n0);
    for (int i = tid; i < nodes * F_IN; i += 128)
        xs[i] = x[(size_t)n0 * F_IN + i];
    __syncthreads();

    if (tid < nodes) {
        const int n = n0 + tid;
        float a0[F_HID], a1[F_HID], ar[F_HID];
        #pragma unroll
        for (int c = 0; c < F_HID; ++c) { a0[c] = 0.f; a1[c] = 0.f; ar[c] = 0.f; }
        const float* xr = &xs[tid * F_IN];
        for (int f = 0; f < F_IN; ++f) {
            const float xv = xr[f];
            #pragma unroll
            for (int c = 0; c < F_HID; ++c) {
                a0[c] = fmaf(xv, w0s[f * F_HID + c], a0[c]);
                a1[c] = fmaf(xv, w1s[f * F_HID + c], a1[c]);
                ar[c] = fmaf(xv, rs [f * F_HID + c], ar[c]);
            }
        }
        #pragma unroll
        for (int c = 0; c < F_HID; ++c) {
            hp[(size_t)n * F_HID + c] = __floats2half2_rn(a0[c], a1[c]);
            r1[(size_t)n * F_HID + c] = ar[c] + bs[c];
        }
    }
}

// ---------------- Degree histogram: LDS-binned, atomic-free merge ----------
// grid (HB, 2). Block (bx,p) scans edge chunk bx, counts dst in
// [p*HRANGE, (p+1)*HRANGE) into u8 LDS bins, writes its slice of partial.
__global__ __launch_bounds__(256) void k_hist(
    const int* __restrict__ edst, unsigned char* __restrict__ partial)
{
    __shared__ unsigned int bins[HRANGE / 4];   // 50 KB, u8 bins packed in u32
    const int bx = blockIdx.x, p = blockIdx.y;
    const int base = p * HRANGE;
    for (int i = threadIdx.x; i < HRANGE / 4; i += 256) bins[i] = 0;
    __syncthreads();

    const int chunk = N_EDGES / HB;             // 50000
    const int e0 = bx * chunk;
    const int e1 = min(N_EDGES, e0 + chunk);
    for (int e = e0 + threadIdx.x; e < e1; e += 256) {
        const unsigned int d = (unsigned int)(edst[e] - base);
        if (d < HRANGE)
            atomicAdd(&bins[d >> 2], 1u << ((d & 3) * 8));  // max degree ~60 << 255
    }
    __syncthreads();

    unsigned int* dp = (unsigned int*)(partial + (size_t)bx * N_NODES + base);
    for (int i = threadIdx.x; i < HRANGE / 4; i += 256) dp[i] = bins[i];
}

// invcnt[n] = 1 / max(degree, 1)
__global__ __launch_bounds__(256) void k_hreduce(
    const unsigned char* __restrict__ partial, float* __restrict__ invcnt)
{
    const int g = blockIdx.x * 256 + threadIdx.x;   // group of 4 nodes
    if (g >= N_NODES / 4) return;
    unsigned int s0 = 0, s1 = 0, s2 = 0, s3 = 0;
    for (int b = 0; b < HB; ++b) {
        const unsigned int v = *(const unsigned int*)(partial + (size_t)b * N_NODES + g * 4);
        s0 += v & 0xffu; s1 += (v >> 8) & 0xffu; s2 += (v >> 16) & 0xffu; s3 += (v >> 24) & 0xffu;
    }
    float4 r;
    r.x = 1.0f / (float)max(s0, 1u);
    r.y = 1.0f / (float)max(s1, 1u);
    r.z = 1.0f / (float)max(s2, 1u);
    r.w = 1.0f / (float)max(s3, 1u);
    ((float4*)invcnt)[g] = r;
}

// ---------------- Layer-1 edge scatter: 8 lanes/edge, pk_f16 atomics -------
__global__ __launch_bounds__(256) void k_edge1(
    const int* __restrict__ esrc, const int* __restrict__ edst,
    const float* __restrict__ attr, const __half2* __restrict__ hp,
    __half2* __restrict__ sum1h)
{
    const int gtid   = blockIdx.x * 256 + threadIdx.x;
    const int stride = gridDim.x * 256;
    const int j  = gtid & 7;        // feature-pair index (features 2j, 2j+1)
    const int estep = stride >> 3;
    for (int e = gtid >> 3; e < N_EDGES; e += estep) {
        const int   s = esrc[e];
        const int   d = edst[e];
        const float u = attr[e];
        const float2 a = __half22float2(hp[(size_t)s * F_HID + 2 * j]);
        const float2 b = __half22float2(hp[(size_t)s * F_HID + 2 * j + 1]);
        const float w0 = 1.0f - u;
        const __half2 m = __floats2half2_rn(w0 * a.x + u * a.y, w0 * b.x + u * b.y);
        unsafeAtomicAdd(&sum1h[(size_t)d * 8 + j], m);   // 8 adjacent lanes = 1 sector
    }
}

// ---------------- Kernel C: finalize layer 1 + layer-2 node transforms -----
__global__ __launch_bounds__(256) void k_mid(
    const __half2* __restrict__ sum1h, const float* __restrict__ invcnt,
    const float* __restrict__ r1,
    const float* __restrict__ W2, const float* __restrict__ root2,
    const float* __restrict__ b2,
    float4* __restrict__ h2, float2* __restrict__ r2)
{
    __shared__ float w2s[2 * F_HID * F_OUT];
    __shared__ float rts[F_HID * F_OUT];
    __shared__ float b2s[F_OUT];
    const int tid = threadIdx.x;
    if (tid < 2 * F_HID * F_OUT) w2s[tid] = W2[tid];
    if (tid < F_HID * F_OUT)     rts[tid] = root2[tid];
    if (tid < F_OUT)             b2s[tid] = b2[tid];
    __syncthreads();

    const int gtid   = blockIdx.x * 256 + tid;
    const int stride = gridDim.x * 256;
    for (int n = gtid; n < N_NODES; n += stride) {
        const float inv = invcnt[n];
        float h[F_HID];
        #pragma unroll
        for (int k = 0; k < 8; ++k) {
            const float2 s = __half22float2(sum1h[(size_t)n * 8 + k]);
            const float v0 = s.x * inv + r1[(size_t)n * F_HID + 2 * k];
            const float v1 = s.y * inv + r1[(size_t)n * F_HID + 2 * k + 1];
            h[2 * k]     = (v0 > 0.0f) ? v0 : expm1f(v0);
            h[2 * k + 1] = (v1 > 0.0f) ? v1 : expm1f(v1);
        }
        float o00 = 0.f, o01 = 0.f, o10 = 0.f, o11 = 0.f;
        float rr0 = b2s[0], rr1 = b2s[1];
        #pragma unroll
        for (int f = 0; f < F_HID; ++f) {
            o00 = fmaf(h[f], w2s[f * 2 + 0], o00);
            o01 = fmaf(h[f], w2s[f * 2 + 1], o01);
            o10 = fmaf(h[f], w2s[2 * F_HID + f * 2 + 0], o10);
            o11 = fmaf(h[f], w2s[2 * F_HID + f * 2 + 1], o11);
            rr0 = fmaf(h[f], rts[f * 2 + 0], rr0);
            rr1 = fmaf(h[f], rts[f * 2 + 1], rr1);
        }
        h2[n] = make_float4(o00, o01, o10, o11);
        r2[n] = make_float2(rr0, rr1);
    }
}

// ---------------- Layer-2 edge scatter: 1 thread/edge, one pk_f16 atomic ---
__global__ __launch_bounds__(256) void k_edge2(
    const int* __restrict__ esrc, const int* __restrict__ edst,
    const float* __restrict__ attr, const float4* __restrict__ h2,
    __half2* __restrict__ sum2h)
{
    const int gtid   = blockIdx.x * 256 + threadIdx.x;
    const int stride = gridDim.x * 256;
    for (int e = gtid; e < N_EDGES; e += stride) {
        const int   s = esrc[e];
        const int   d = edst[e];
        const float u = attr[e];
        const float4 h = h2[s];
        const float w0 = 1.0f - u;
        const __half2 m = __floats2half2_rn(w0 * h.x + u * h.z, w0 * h.y + u * h.w);
        unsafeAtomicAdd(&sum2h[d], m);
    }
}

// ---------------- Kernel E: finalize layer 2 + log_softmax ----------------
__global__ __launch_bounds__(256) void k_final(
    const __half2* __restrict__ sum2h, const float* __restrict__ invcnt,
    const float2* __restrict__ r2, float2* __restrict__ out)
{
    const int gtid   = blockIdx.x * 256 + threadIdx.x;
    const int stride = gridDim.x * 256;
    for (int n = gtid; n < N_NODES; n += stride) {
        const float inv = invcnt[n];
        const float2 s = __half22float2(sum2h[n]);
        const float2 r = r2[n];
        const float o0 = s.x * inv + r.x;
        const float o1 = s.y * inv + r.y;
        const float m  = fmaxf(o0, o1);
        const float l  = m + logf(expf(o0 - m) + expf(o1 - m));
        out[n] = make_float2(o0 - l, o1 - l);
    }
}

extern "C" void kernel_launch(void* const* d_in, const int* in_sizes, int n_in,
                              void* d_out, int out_size, void* d_ws, size_t ws_size,
                              hipStream_t stream) {
    const float* x     = (const float*)d_in[0];
    const int*   ei    = (const int*)  d_in[1];   // [2][N_EDGES]
    const float* attr  = (const float*)d_in[2];
    const float* W1    = (const float*)d_in[4];
    const float* root1 = (const float*)d_in[5];
    const float* b1    = (const float*)d_in[6];
    const float* W2    = (const float*)d_in[7];
    const float* root2 = (const float*)d_in[8];
    const float* b2    = (const float*)d_in[9];
    float2* out = (float2*)d_out;

    char* ws = (char*)d_ws;
    size_t off = 0;
    __half2* hp    = (__half2*)(ws + off); off += (size_t)N_NODES * F_HID * sizeof(__half2); // 6.4MB
    float*   r1    = (float*)  (ws + off); off += (size_t)N_NODES * F_HID * sizeof(float);   // 6.4MB
    float4*  h2    = (float4*) (ws + off); off += (size_t)N_NODES * sizeof(float4);          // 1.6MB
    float2*  r2    = (float2*) (ws + off); off += (size_t)N_NODES * sizeof(float2);          // 0.8MB
    __half2* sum1h = (__half2*)(ws + off); off += (size_t)N_NODES * 8 * sizeof(__half2);     // 3.2MB
    __half2* sum2h = (__half2*)(ws + off); off += (size_t)N_NODES * sizeof(__half2);         // 0.4MB
    float*   invcnt= (float*)  (ws + off); off += (size_t)N_NODES * sizeof(float);           // 0.4MB
    unsigned char* partial = (unsigned char*)(ws + off); off += (size_t)HB * N_NODES;        // 6.4MB

    // zero the two f16 accumulators (contiguous)
    hipMemsetAsync(sum1h, 0, (size_t)N_NODES * 8 * sizeof(__half2)
                           + (size_t)N_NODES * sizeof(__half2), stream);

    const int* esrc = ei;
    const int* edst = ei + N_EDGES;

    k_hist    <<<dim3(HB, 2), 256, 0, stream>>>(edst, partial);
    k_hreduce <<<(N_NODES / 4 + 255) / 256, 256, 0, stream>>>(partial, invcnt);
    k_transform1<<<(N_NODES + 127) / 128, 128, 0, stream>>>(x, W1, root1, b1, hp, r1);
    k_edge1   <<<2048, 256, 0, stream>>>(esrc, edst, attr, hp, sum1h);
    k_mid     <<<512, 256, 0, stream>>>(sum1h, invcnt, r1, W2, root2, b2, h2, r2);
    k_edge2   <<<2048, 256, 0, stream>>>(esrc, edst, attr, h2, sum2h);
    k_final   <<<256, 256, 0, stream>>>(sum2h, invcnt, r2, out);
}

// Round 3
// 432.216 us; speedup vs baseline: 1.6387x; 1.0369x over previous
//
#include <hip/hip_runtime.h>
#include <hip/hip_fp16.h>

#define N_NODES 100000
#define N_EDGES 3200000
#define F_IN    61
#define F_HID   16
#define F_OUT   2
#define HB      64       // edge chunks (scatter/hist blocks in x)
#define CHUNK   (N_EDGES / HB)          // 50000
#define HRANGE  50000    // node-range per pass (grid.y = 2 passes)
#define NSCAN_B 391      // ceil(N_NODES/256)

typedef unsigned int uint;

// ---------------- layer-1 node transforms ----------------
// hp[n][c] = half2(h0[c], h1[c]);  r1[n][c] = (x @ root1 + b1)[c]  (f32)
__global__ __launch_bounds__(128) void k_transform1(
    const float* __restrict__ x, const float* __restrict__ W1,
    const float* __restrict__ root1, const float* __restrict__ b1,
    __half2* __restrict__ hp, float* __restrict__ r1)
{
    __shared__ float xs[128 * F_IN];
    __shared__ float w0s[F_IN * F_HID];
    __shared__ float w1s[F_IN * F_HID];
    __shared__ float rs [F_IN * F_HID];
    __shared__ float bs [F_HID];

    const int tid = threadIdx.x;
    for (int i = tid; i < F_IN * F_HID; i += 128) {
        w0s[i] = W1[i];
        w1s[i] = W1[F_IN * F_HID + i];
        rs[i]  = root1[i];
    }
    if (tid < F_HID) bs[tid] = b1[tid];

    const int n0 = blockIdx.x * 128;
    const int nodes = min(128, N_NODES - n0);
    for (int i = tid; i < nodes * F_IN; i += 128)
        xs[i] = x[(size_t)n0 * F_IN + i];
    __syncthreads();

    if (tid < nodes) {
        const int n = n0 + tid;
        float a0[F_HID], a1[F_HID], ar[F_HID];
        #pragma unroll
        for (int c = 0; c < F_HID; ++c) { a0[c] = 0.f; a1[c] = 0.f; ar[c] = 0.f; }
        const float* xr = &xs[tid * F_IN];
        for (int f = 0; f < F_IN; ++f) {
            const float xv = xr[f];
            #pragma unroll
            for (int c = 0; c < F_HID; ++c) {
                a0[c] = fmaf(xv, w0s[f * F_HID + c], a0[c]);
                a1[c] = fmaf(xv, w1s[f * F_HID + c], a1[c]);
                ar[c] = fmaf(xv, rs [f * F_HID + c], ar[c]);
            }
        }
        #pragma unroll
        for (int c = 0; c < F_HID; ++c) {
            hp[(size_t)n * F_HID + c] = __floats2half2_rn(a0[c], a1[c]);
            r1[(size_t)n * F_HID + c] = ar[c] + bs[c];
        }
    }
}

// ---------------- degree histogram (per-chunk u8 counts) ----------------
__global__ __launch_bounds__(256) void k_hist(
    const int* __restrict__ edst, unsigned char* __restrict__ partial)
{
    __shared__ uint bins[HRANGE / 4];   // 50 KB
    const int bx = blockIdx.x, p = blockIdx.y;
    const int base = p * HRANGE;
    for (int i = threadIdx.x; i < HRANGE / 4; i += 256) bins[i] = 0;
    __syncthreads();

    const int e0 = bx * CHUNK, e1 = e0 + CHUNK;
    for (int e = e0 + threadIdx.x; e < e1; e += 256) {
        const uint d = (uint)(edst[e] - base);
        if (d < HRANGE)
            atomicAdd(&bins[d >> 2], 1u << ((d & 3) * 8));   // deg << 255
    }
    __syncthreads();

    uint* dp = (uint*)(partial + (size_t)bx * N_NODES + base);
    for (int i = threadIdx.x; i < HRANGE / 4; i += 256) dp[i] = bins[i];
}

// ---- per-(chunk,node) exclusive prefix over chunks; degree[n] out --------
__global__ __launch_bounds__(256) void k_prep(
    unsigned char* __restrict__ partial, uint* __restrict__ degree)
{
    const int g = blockIdx.x * 256 + threadIdx.x;   // node-group of 4
    if (g >= N_NODES / 4) return;
    uint r0 = 0, r1 = 0, r2 = 0, r3 = 0;
    for (int b = 0; b < HB; ++b) {
        uint* w = (uint*)(partial + (size_t)b * N_NODES) + g;
        const uint v = *w;
        *w = r0 | (r1 << 8) | (r2 << 16) | (r3 << 24);
        r0 += v & 0xffu; r1 += (v >> 8) & 0xffu; r2 += (v >> 16) & 0xffu; r3 += (v >> 24) & 0xffu;
    }
    ((uint4*)degree)[g] = make_uint4(r0, r1, r2, r3);
}

// ---------------- rowptr = exclusive scan of degree ----------------
__global__ __launch_bounds__(256) void k_scan1(
    const uint* __restrict__ degree, uint* __restrict__ rowptr, uint* __restrict__ bsum)
{
    __shared__ uint s[256];
    const int tid = threadIdx.x;
    const int g = blockIdx.x * 256 + tid;
    const uint v = (g < N_NODES) ? degree[g] : 0u;
    s[tid] = v; __syncthreads();
    for (int off = 1; off < 256; off <<= 1) {
        const uint t = (tid >= off) ? s[tid - off] : 0u;
        __syncthreads();
        s[tid] += t;
        __syncthreads();
    }
    if (g < N_NODES) rowptr[g] = s[tid] - v;
    if (tid == 255) bsum[blockIdx.x] = s[255];
}

__global__ __launch_bounds__(512) void k_scan2(uint* __restrict__ bsum)
{
    __shared__ uint s[512];
    const int tid = threadIdx.x;
    const uint v = (tid < NSCAN_B) ? bsum[tid] : 0u;
    s[tid] = v; __syncthreads();
    for (int off = 1; off < 512; off <<= 1) {
        const uint t = (tid >= off) ? s[tid - off] : 0u;
        __syncthreads();
        s[tid] += t;
        __syncthreads();
    }
    if (tid < NSCAN_B) bsum[tid] = s[tid] - v;
}

__global__ __launch_bounds__(256) void k_scan3(
    uint* __restrict__ rowptr, const uint* __restrict__ bsum)
{
    const int g = blockIdx.x * 256 + threadIdx.x;
    if (g < N_NODES) rowptr[g] += bsum[blockIdx.x];
    if (blockIdx.x == 0 && threadIdx.x == 0) rowptr[N_NODES] = N_EDGES;
}

// ---------------- CSR scatter: LDS-atomic local rank, plain global stores --
__global__ __launch_bounds__(256) void k_scatter(
    const int* __restrict__ esrc, const int* __restrict__ edst,
    const float* __restrict__ attr,
    const unsigned char* __restrict__ partial, const uint* __restrict__ rowptr,
    uint2* __restrict__ vals)
{
    __shared__ uint bins[HRANGE / 4];   // 50 KB, u8 running counters
    const int bx = blockIdx.x, p = blockIdx.y;
    const int base = p * HRANGE;
    for (int i = threadIdx.x; i < HRANGE / 4; i += 256) bins[i] = 0;
    __syncthreads();

    const unsigned char* pre = partial + (size_t)bx * N_NODES;
    const int e0 = bx * CHUNK, e1 = e0 + CHUNK;
    for (int e = e0 + threadIdx.x; e < e1; e += 256) {
        const int d = edst[e];
        const uint dr = (uint)(d - base);
        if (dr < HRANGE) {
            const uint sh  = (dr & 3) * 8;
            const uint old = atomicAdd(&bins[dr >> 2], 1u << sh);
            const uint local = (old >> sh) & 0xffu;
            const uint pos = rowptr[d] + (uint)pre[d] + local;
            vals[pos] = make_uint2((uint)esrc[e], __float_as_uint(attr[e]));
        }
    }
}

// ---------------- layer-1 pull aggregate + ELU + layer-2 transforms --------
// wave per node; lanes = 4 edge-groups x 16 features. No atomics.
__global__ __launch_bounds__(256) void k_agg1(
    const uint* __restrict__ rowptr, const uint2* __restrict__ vals,
    const __half2* __restrict__ hp, const float* __restrict__ r1,
    const float* __restrict__ W2, const float* __restrict__ root2,
    const float* __restrict__ b2,
    float4* __restrict__ h2, float2* __restrict__ r2)
{
    __shared__ float w2s[2 * F_HID * F_OUT];
    __shared__ float rts[F_HID * F_OUT];
    __shared__ float b2s[F_OUT];
    const int tid = threadIdx.x;
    if (tid < 2 * F_HID * F_OUT) w2s[tid] = W2[tid];
    if (tid < F_HID * F_OUT)     rts[tid] = root2[tid];
    if (tid < F_OUT)             b2s[tid] = b2[tid];
    __syncthreads();

    const int lane = tid & 63;
    const int wave = tid >> 6;
    const int n = blockIdx.x * 4 + wave;
    const int ep = lane >> 4;          // 0..3
    const int c  = lane & 15;          // feature

    const uint r0 = rowptr[n];
    const uint deg = rowptr[n + 1] - r0;

    float acc = 0.f;
    for (uint i = ep; i < deg; i += 4) {
        const uint2 v = vals[r0 + i];
        const float u = __uint_as_float(v.y);
        const float2 h = __half22float2(hp[(size_t)v.x * F_HID + c]);
        acc += (1.0f - u) * h.x + u * h.y;
    }
    acc += __shfl_xor(acc, 16);
    acc += __shfl_xor(acc, 32);

    const float inv = 1.0f / (float)max(deg, 1u);
    const float vv = acc * inv + r1[(size_t)n * F_HID + c];
    const float hcf = (vv > 0.0f) ? vv : expm1f(vv);   // ELU

    float o00 = 0.f, o01 = 0.f, o10 = 0.f, o11 = 0.f;
    float rr0 = b2s[0], rr1 = b2s[1];
    #pragma unroll
    for (int f = 0; f < F_HID; ++f) {
        const float hv = __shfl(hcf, f);
        o00 = fmaf(hv, w2s[f * 2 + 0], o00);
        o01 = fmaf(hv, w2s[f * 2 + 1], o01);
        o10 = fmaf(hv, w2s[2 * F_HID + f * 2 + 0], o10);
        o11 = fmaf(hv, w2s[2 * F_HID + f * 2 + 1], o11);
        rr0 = fmaf(hv, rts[f * 2 + 0], rr0);
        rr1 = fmaf(hv, rts[f * 2 + 1], rr1);
    }
    if (lane == 0) {
        h2[n] = make_float4(o00, o10, o01, o11);   // [feat0:(k0,k1), feat1:(k0,k1)]
        r2[n] = make_float2(rr0, rr1);
    }
}

// ---------------- layer-2 pull aggregate + log_softmax --------------------
// wave per node; lanes = 32 edge-groups x 2 features.
__global__ __launch_bounds__(256) void k_agg2(
    const uint* __restrict__ rowptr, const uint2* __restrict__ vals,
    const float2* __restrict__ h2f2, const float2* __restrict__ r2,
    float* __restrict__ out)
{
    const int tid = threadIdx.x;
    const int lane = tid & 63;
    const int wave = tid >> 6;
    const int n = blockIdx.x * 4 + wave;
    const int ep = lane >> 1;          // 0..31
    const int fp = lane & 1;           // feature

    const uint r0 = rowptr[n];
    const uint deg = rowptr[n + 1] - r0;

    float acc = 0.f;
    for (uint i = ep; i < deg; i += 32) {
        const uint2 v = vals[r0 + i];
        const float u = __uint_as_float(v.y);
        const float2 g = h2f2[(size_t)v.x * 2 + fp];
        acc += (1.0f - u) * g.x + u * g.y;
    }
    #pragma unroll
    for (int off = 2; off < 64; off <<= 1) acc += __shfl_xor(acc, off);

    const float inv = 1.0f / (float)max(deg, 1u);
    const float rv = fp ? r2[n].y : r2[n].x;
    const float o = acc * inv + rv;
    const float other = __shfl_xor(o, 1);
    const float m = fmaxf(o, other);
    const float l = m + logf(expf(o - m) + expf(other - m));
    if (lane < 2) out[(size_t)n * 2 + fp] = o - l;
}

extern "C" void kernel_launch(void* const* d_in, const int* in_sizes, int n_in,
                              void* d_out, int out_size, void* d_ws, size_t ws_size,
                              hipStream_t stream) {
    const float* x     = (const float*)d_in[0];
    const int*   ei    = (const int*)  d_in[1];   // [2][N_EDGES]
    const float* attr  = (const float*)d_in[2];
    const float* W1    = (const float*)d_in[4];
    const float* root1 = (const float*)d_in[5];
    const float* b1    = (const float*)d_in[6];
    const float* W2    = (const float*)d_in[7];
    const float* root2 = (const float*)d_in[8];
    const float* b2    = (const float*)d_in[9];
    float* out = (float*)d_out;

    char* ws = (char*)d_ws;
    size_t off = 0;
    __half2* hp    = (__half2*)(ws + off); off += (size_t)N_NODES * F_HID * sizeof(__half2); // 6.4MB
    float*   r1    = (float*)  (ws + off); off += (size_t)N_NODES * F_HID * sizeof(float);   // 6.4MB
    float4*  h2    = (float4*) (ws + off); off += (size_t)N_NODES * sizeof(float4);          // 1.6MB
    float2*  r2    = (float2*) (ws + off); off += (size_t)N_NODES * sizeof(float2);          // 0.8MB
    uint2*   vals  = (uint2*)  (ws + off); off += (size_t)N_EDGES * sizeof(uint2);           // 25.6MB
    uint*    rowptr= (uint*)   (ws + off); off += (size_t)(N_NODES + 1) * sizeof(uint);
    uint*    degree= (uint*)   (ws + off); off += (size_t)N_NODES * sizeof(uint);
    uint*    bsum  = (uint*)   (ws + off); off += (size_t)512 * sizeof(uint);
    unsigned char* partial = (unsigned char*)(ws + off); off += (size_t)HB * N_NODES;        // 6.4MB

    const int* esrc = ei;
    const int* edst = ei + N_EDGES;

    k_hist     <<<dim3(HB, 2), 256, 0, stream>>>(edst, partial);
    k_prep     <<<(N_NODES / 4 + 255) / 256, 256, 0, stream>>>(partial, degree);
    k_scan1    <<<NSCAN_B, 256, 0, stream>>>(degree, rowptr, bsum);
    k_scan2    <<<1, 512, 0, stream>>>(bsum);
    k_scan3    <<<NSCAN_B, 256, 0, stream>>>(rowptr, bsum);
    k_scatter  <<<dim3(HB, 2), 256, 0, stream>>>(esrc, edst, attr, partial, rowptr, vals);
    k_transform1<<<(N_NODES + 127) / 128, 128, 0, stream>>>(x, W1, root1, b1, hp, r1);
    k_agg1     <<<N_NODES / 4, 256, 0, stream>>>(rowptr, vals, hp, r1, W2, root2, b2, h2, r2);
    k_agg2     <<<N_NODES / 4, 256, 0, stream>>>(rowptr, vals, (const float2*)h2, r2, out);
}

// Round 4
// 362.002 us; speedup vs baseline: 1.9565x; 1.1940x over previous
//
#include <hip/hip_runtime.h>
#include <hip/hip_fp16.h>

#define N_NODES 100000
#define N_EDGES 3200000
#define F_IN    61
#define F_HID   16
#define F_OUT   2
#define HB      256                    // edge chunks
#define CHUNK   (N_EDGES / HB)         // 12500
#define PASSES  4
#define HRANGE  25000                  // node-range per pass
#define NSCAN_B 391                    // ceil(N_NODES/256)

typedef unsigned int uint;

// ---------------- layer-1 node transforms ----------------
// hp[n][c] = half2(h0[c], h1[c]);  r1[n][c] = (x @ root1 + b1)[c]  (f32)
__global__ __launch_bounds__(128) void k_transform1(
    const float* __restrict__ x, const float* __restrict__ W1,
    const float* __restrict__ root1, const float* __restrict__ b1,
    __half2* __restrict__ hp, float* __restrict__ r1)
{
    __shared__ float xs[128 * F_IN];
    __shared__ float w0s[F_IN * F_HID];
    __shared__ float w1s[F_IN * F_HID];
    __shared__ float rs [F_IN * F_HID];
    __shared__ float bs [F_HID];

    const int tid = threadIdx.x;
    for (int i = tid; i < F_IN * F_HID; i += 128) {
        w0s[i] = W1[i];
        w1s[i] = W1[F_IN * F_HID + i];
        rs[i]  = root1[i];
    }
    if (tid < F_HID) bs[tid] = b1[tid];

    const int n0 = blockIdx.x * 128;
    const int nodes = min(128, N_NODES - n0);
    for (int i = tid; i < nodes * F_IN; i += 128)
        xs[i] = x[(size_t)n0 * F_IN + i];
    __syncthreads();

    if (tid < nodes) {
        const int n = n0 + tid;
        float a0[F_HID], a1[F_HID], ar[F_HID];
        #pragma unroll
        for (int c = 0; c < F_HID; ++c) { a0[c] = 0.f; a1[c] = 0.f; ar[c] = 0.f; }
        const float* xr = &xs[tid * F_IN];
        for (int f = 0; f < F_IN; ++f) {
            const float xv = xr[f];
            #pragma unroll
            for (int c = 0; c < F_HID; ++c) {
                a0[c] = fmaf(xv, w0s[f * F_HID + c], a0[c]);
                a1[c] = fmaf(xv, w1s[f * F_HID + c], a1[c]);
                ar[c] = fmaf(xv, rs [f * F_HID + c], ar[c]);
            }
        }
        #pragma unroll
        for (int c = 0; c < F_HID; ++c) {
            hp[(size_t)n * F_HID + c] = __floats2half2_rn(a0[c], a1[c]);
            r1[(size_t)n * F_HID + c] = ar[c] + bs[c];
        }
    }
}

// ---------------- degree histogram (per-chunk u8 counts) ----------------
// grid (HB, PASSES); block (bx,p) counts dst of chunk bx within pass-p range.
__global__ __launch_bounds__(256) void k_hist(
    const int* __restrict__ edst, unsigned char* __restrict__ partial)
{
    __shared__ uint bins[HRANGE / 4];   // 25 KB
    const int bx = blockIdx.x, p = blockIdx.y;
    const int base = p * HRANGE;
    for (int i = threadIdx.x; i < HRANGE / 4; i += 256) bins[i] = 0;
    __syncthreads();

    const int e0 = bx * CHUNK, e1 = e0 + CHUNK;
    for (int e = e0 + threadIdx.x; e < e1; e += 256) {
        const uint d = (uint)(edst[e] - base);
        if (d < HRANGE)
            atomicAdd(&bins[d >> 2], 1u << ((d & 3) * 8));
    }
    __syncthreads();

    uint* dp = (uint*)(partial + (size_t)bx * N_NODES + base);
    for (int i = threadIdx.x; i < HRANGE / 4; i += 256) dp[i] = bins[i];
}

// ---- per-(chunk,node) exclusive prefix over chunks; degree[n] out --------
__global__ __launch_bounds__(256) void k_prep(
    unsigned char* __restrict__ partial, uint* __restrict__ degree)
{
    const int g = blockIdx.x * 256 + threadIdx.x;   // node-group of 4
    if (g >= N_NODES / 4) return;
    uint r0 = 0, r1 = 0, r2 = 0, r3 = 0;
    for (int b = 0; b < HB; ++b) {
        uint* w = (uint*)(partial + (size_t)b * N_NODES) + g;
        const uint v = *w;
        *w = r0 | (r1 << 8) | (r2 << 16) | (r3 << 24);
        r0 += v & 0xffu; r1 += (v >> 8) & 0xffu; r2 += (v >> 16) & 0xffu; r3 += (v >> 24) & 0xffu;
    }
    ((uint4*)degree)[g] = make_uint4(r0, r1, r2, r3);
}

// ---------------- rowptr = exclusive scan of degree ----------------
__global__ __launch_bounds__(256) void k_scan1(
    const uint* __restrict__ degree, uint* __restrict__ rowptr, uint* __restrict__ bsum)
{
    __shared__ uint s[256];
    const int tid = threadIdx.x;
    const int g = blockIdx.x * 256 + tid;
    const uint v = (g < N_NODES) ? degree[g] : 0u;
    s[tid] = v; __syncthreads();
    for (int off = 1; off < 256; off <<= 1) {
        const uint t = (tid >= off) ? s[tid - off] : 0u;
        __syncthreads();
        s[tid] += t;
        __syncthreads();
    }
    if (g < N_NODES) rowptr[g] = s[tid] - v;
    if (tid == 255) bsum[blockIdx.x] = s[255];
}

__global__ __launch_bounds__(512) void k_scan2(uint* __restrict__ bsum)
{
    __shared__ uint s[512];
    const int tid = threadIdx.x;
    const uint v = (tid < NSCAN_B) ? bsum[tid] : 0u;
    s[tid] = v; __syncthreads();
    for (int off = 1; off < 512; off <<= 1) {
        const uint t = (tid >= off) ? s[tid - off] : 0u;
        __syncthreads();
        s[tid] += t;
        __syncthreads();
    }
    if (tid < NSCAN_B) bsum[tid] = s[tid] - v;
}

__global__ __launch_bounds__(256) void k_scan3(
    uint* __restrict__ rowptr, const uint* __restrict__ bsum)
{
    const int g = blockIdx.x * 256 + threadIdx.x;
    if (g < N_NODES) rowptr[g] += bsum[blockIdx.x];
    if (blockIdx.x == 0 && threadIdx.x == 0) rowptr[N_NODES] = N_EDGES;
}

// ---------------- CSR scatter: LDS-atomic local rank, plain global stores --
__global__ __launch_bounds__(256) void k_scatter(
    const int* __restrict__ esrc, const int* __restrict__ edst,
    const float* __restrict__ attr,
    const unsigned char* __restrict__ partial, const uint* __restrict__ rowptr,
    uint2* __restrict__ vals)
{
    __shared__ uint bins[HRANGE / 4];   // 25 KB, u8 running counters
    const int bx = blockIdx.x, p = blockIdx.y;
    const int base = p * HRANGE;
    for (int i = threadIdx.x; i < HRANGE / 4; i += 256) bins[i] = 0;
    __syncthreads();

    const unsigned char* pre = partial + (size_t)bx * N_NODES;
    const int e0 = bx * CHUNK, e1 = e0 + CHUNK;
    for (int e = e0 + threadIdx.x; e < e1; e += 256) {
        const int d = edst[e];
        const uint dr = (uint)(d - base);
        if (dr < HRANGE) {
            const uint sh  = (dr & 3) * 8;
            const uint old = atomicAdd(&bins[dr >> 2], 1u << sh);
            const uint local = (old >> sh) & 0xffu;
            const uint pos = rowptr[d] + (uint)pre[d] + local;
            vals[pos] = make_uint2((uint)esrc[e], __float_as_uint(attr[e]));
        }
    }
}

// ---------------- layer-1 pull aggregate + ELU + layer-2 transforms --------
// wave per node; lanes = 4 edge-groups x 16 features. No atomics.
__global__ __launch_bounds__(256) void k_agg1(
    const uint* __restrict__ rowptr, const uint2* __restrict__ vals,
    const __half2* __restrict__ hp, const float* __restrict__ r1,
    const float* __restrict__ W2, const float* __restrict__ root2,
    const float* __restrict__ b2,
    float4* __restrict__ h2, float2* __restrict__ r2)
{
    __shared__ float w2s[2 * F_HID * F_OUT];
    __shared__ float rts[F_HID * F_OUT];
    __shared__ float b2s[F_OUT];
    const int tid = threadIdx.x;
    if (tid < 2 * F_HID * F_OUT) w2s[tid] = W2[tid];
    if (tid < F_HID * F_OUT)     rts[tid] = root2[tid];
    if (tid < F_OUT)             b2s[tid] = b2[tid];
    __syncthreads();

    const int lane = tid & 63;
    const int wave = tid >> 6;
    const int n = blockIdx.x * 4 + wave;
    const int ep = lane >> 4;          // 0..3
    const int c  = lane & 15;          // feature

    const uint r0 = rowptr[n];
    const uint deg = rowptr[n + 1] - r0;

    float acc = 0.f;
    for (uint i = ep; i < deg; i += 4) {
        const uint2 v = vals[r0 + i];
        const float u = __uint_as_float(v.y);
        const float2 h = __half22float2(hp[(size_t)v.x * F_HID + c]);
        acc += (1.0f - u) * h.x + u * h.y;
    }
    acc += __shfl_xor(acc, 16);
    acc += __shfl_xor(acc, 32);

    const float inv = 1.0f / (float)max(deg, 1u);
    const float vv = acc * inv + r1[(size_t)n * F_HID + c];
    const float hcf = (vv > 0.0f) ? vv : expm1f(vv);   // ELU

    float o00 = 0.f, o01 = 0.f, o10 = 0.f, o11 = 0.f;
    float rr0 = b2s[0], rr1 = b2s[1];
    #pragma unroll
    for (int f = 0; f < F_HID; ++f) {
        const float hv = __shfl(hcf, f);
        o00 = fmaf(hv, w2s[f * 2 + 0], o00);
        o01 = fmaf(hv, w2s[f * 2 + 1], o01);
        o10 = fmaf(hv, w2s[2 * F_HID + f * 2 + 0], o10);
        o11 = fmaf(hv, w2s[2 * F_HID + f * 2 + 1], o11);
        rr0 = fmaf(hv, rts[f * 2 + 0], rr0);
        rr1 = fmaf(hv, rts[f * 2 + 1], rr1);
    }
    if (lane == 0) {
        h2[n] = make_float4(o00, o10, o01, o11);   // [feat0:(k0,k1), feat1:(k0,k1)]
        r2[n] = make_float2(rr0, rr1);
    }
}

// ---------------- layer-2 pull aggregate + log_softmax --------------------
// wave per node; lanes = 32 edge-groups x 2 features.
__global__ __launch_bounds__(256) void k_agg2(
    const uint* __restrict__ rowptr, const uint2* __restrict__ vals,
    const float2* __restrict__ h2f2, const float2* __restrict__ r2,
    float* __restrict__ out)
{
    const int tid = threadIdx.x;
    const int lane = tid & 63;
    const int wave = tid >> 6;
    const int n = blockIdx.x * 4 + wave;
    const int ep = lane >> 1;          // 0..31
    const int fp = lane & 1;           // feature

    const uint r0 = rowptr[n];
    const uint deg = rowptr[n + 1] - r0;

    float acc = 0.f;
    for (uint i = ep; i < deg; i += 32) {
        const uint2 v = vals[r0 + i];
        const float u = __uint_as_float(v.y);
        const float2 g = h2f2[(size_t)v.x * 2 + fp];
        acc += (1.0f - u) * g.x + u * g.y;
    }
    #pragma unroll
    for (int off = 2; off < 64; off <<= 1) acc += __shfl_xor(acc, off);

    const float inv = 1.0f / (float)max(deg, 1u);
    const float rv = fp ? r2[n].y : r2[n].x;
    const float o = acc * inv + rv;
    const float other = __shfl_xor(o, 1);
    const float m = fmaxf(o, other);
    const float l = m + logf(expf(o - m) + expf(other - m));
    if (lane < 2) out[(size_t)n * 2 + fp] = o - l;
}

extern "C" void kernel_launch(void* const* d_in, const int* in_sizes, int n_in,
                              void* d_out, int out_size, void* d_ws, size_t ws_size,
                              hipStream_t stream) {
    const float* x     = (const float*)d_in[0];
    const int*   ei    = (const int*)  d_in[1];   // [2][N_EDGES]
    const float* attr  = (const float*)d_in[2];
    const float* W1    = (const float*)d_in[4];
    const float* root1 = (const float*)d_in[5];
    const float* b1    = (const float*)d_in[6];
    const float* W2    = (const float*)d_in[7];
    const float* root2 = (const float*)d_in[8];
    const float* b2    = (const float*)d_in[9];
    float* out = (float*)d_out;

    char* ws = (char*)d_ws;
    size_t off = 0;
    uint2*   vals  = (uint2*)  (ws + off); off += (size_t)N_EDGES * sizeof(uint2);       // 25.6MB
    uint*    rowptr= (uint*)   (ws + off); off += (size_t)(N_NODES + 1) * sizeof(uint);
    uint*    degree= (uint*)   (ws + off); off += (size_t)N_NODES * sizeof(uint);
    uint*    bsum  = (uint*)   (ws + off); off += (size_t)512 * sizeof(uint);
    off = (off + 255) & ~(size_t)255;
    unsigned char* partial = (unsigned char*)(ws + off); off += (size_t)HB * N_NODES;    // 25.6MB

    // partial is dead after k_scatter; alias the node-transform buffers onto it
    // (stream-ordered: k_transform1 launches after k_scatter).
    char* alias = (char*)partial;
    size_t aoff = 0;
    __half2* hp = (__half2*)(alias + aoff); aoff += (size_t)N_NODES * F_HID * sizeof(__half2); // 6.4MB
    float*   r1 = (float*)  (alias + aoff); aoff += (size_t)N_NODES * F_HID * sizeof(float);   // 6.4MB
    float4*  h2 = (float4*) (alias + aoff); aoff += (size_t)N_NODES * sizeof(float4);          // 1.6MB
    float2*  r2 = (float2*) (alias + aoff); aoff += (size_t)N_NODES * sizeof(float2);          // 0.8MB

    const int* esrc = ei;
    const int* edst = ei + N_EDGES;

    k_hist     <<<dim3(HB, PASSES), 256, 0, stream>>>(edst, partial);
    k_prep     <<<(N_NODES / 4 + 255) / 256, 256, 0, stream>>>(partial, degree);
    k_scan1    <<<NSCAN_B, 256, 0, stream>>>(degree, rowptr, bsum);
    k_scan2    <<<1, 512, 0, stream>>>(bsum);
    k_scan3    <<<NSCAN_B, 256, 0, stream>>>(rowptr, bsum);
    k_scatter  <<<dim3(HB, PASSES), 256, 0, stream>>>(esrc, edst, attr, partial, rowptr, vals);
    k_transform1<<<(N_NODES + 127) / 128, 128, 0, stream>>>(x, W1, root1, b1, hp, r1);
    k_agg1     <<<N_NODES / 4, 256, 0, stream>>>(rowptr, vals, hp, r1, W2, root2, b2, h2, r2);
    k_agg2     <<<N_NODES / 4, 256, 0, stream>>>(rowptr, vals, (const float2*)h2, r2, out);
}

// Round 6
// 287.414 us; speedup vs baseline: 2.4643x; 1.2595x over previous
//
#include <hip/hip_runtime.h>
#include <hip/hip_fp16.h>

#define N_NODES 100000
#define N_EDGES 3200000
#define F_IN    61
#define F_HID   16
#define F_OUT   2
#define HB      256                    // edge chunks
#define CHUNK   (N_EDGES / HB)         // 12500
#define PASSES  4
#define HRANGE  25000                  // node-range per pass
#define NSCAN_B 391                    // ceil(N_NODES/256)

typedef unsigned int uint;

// ---------------- layer-1 node transforms ----------------
// hp[n][c] = half2(h0[c], h1[c]);  r1[n][c] = (x @ root1 + b1)[c]  (f32)
__global__ __launch_bounds__(128) void k_transform1(
    const float* __restrict__ x, const float* __restrict__ W1,
    const float* __restrict__ root1, const float* __restrict__ b1,
    __half2* __restrict__ hp, float* __restrict__ r1)
{
    __shared__ float xs[128 * F_IN];
    __shared__ float w0s[F_IN * F_HID];
    __shared__ float w1s[F_IN * F_HID];
    __shared__ float rs [F_IN * F_HID];
    __shared__ float bs [F_HID];

    const int tid = threadIdx.x;
    for (int i = tid; i < F_IN * F_HID; i += 128) {
        w0s[i] = W1[i];
        w1s[i] = W1[F_IN * F_HID + i];
        rs[i]  = root1[i];
    }
    if (tid < F_HID) bs[tid] = b1[tid];

    const int n0 = blockIdx.x * 128;
    const int nodes = min(128, N_NODES - n0);
    for (int i = tid; i < nodes * F_IN; i += 128)
        xs[i] = x[(size_t)n0 * F_IN + i];
    __syncthreads();

    if (tid < nodes) {
        const int n = n0 + tid;
        float a0[F_HID], a1[F_HID], ar[F_HID];
        #pragma unroll
        for (int c = 0; c < F_HID; ++c) { a0[c] = 0.f; a1[c] = 0.f; ar[c] = 0.f; }
        const float* xr = &xs[tid * F_IN];
        for (int f = 0; f < F_IN; ++f) {
            const float xv = xr[f];
            #pragma unroll
            for (int c = 0; c < F_HID; ++c) {
                a0[c] = fmaf(xv, w0s[f * F_HID + c], a0[c]);
                a1[c] = fmaf(xv, w1s[f * F_HID + c], a1[c]);
                ar[c] = fmaf(xv, rs [f * F_HID + c], ar[c]);
            }
        }
        #pragma unroll
        for (int c = 0; c < F_HID; ++c) {
            hp[(size_t)n * F_HID + c] = __floats2half2_rn(a0[c], a1[c]);
            r1[(size_t)n * F_HID + c] = ar[c] + bs[c];
        }
    }
}

// ---------------- degree histogram (per-chunk u8 counts) ----------------
__global__ __launch_bounds__(256) void k_hist(
    const int* __restrict__ edst, unsigned char* __restrict__ partial)
{
    __shared__ uint bins[HRANGE / 4];   // 25 KB
    const int bx = blockIdx.x, p = blockIdx.y;
    const int base = p * HRANGE;
    for (int i = threadIdx.x; i < HRANGE / 4; i += 256) bins[i] = 0;
    __syncthreads();

    const int e0 = bx * CHUNK, e1 = e0 + CHUNK;
    for (int e = e0 + threadIdx.x; e < e1; e += 256) {
        const uint d = (uint)(edst[e] - base);
        if (d < HRANGE)
            atomicAdd(&bins[d >> 2], 1u << ((d & 3) * 8));
    }
    __syncthreads();

    uint* dp = (uint*)(partial + (size_t)bx * N_NODES + base);
    for (int i = threadIdx.x; i < HRANGE / 4; i += 256) dp[i] = bins[i];
}

// ---- per-(chunk,node) exclusive prefix over chunks; degree[n] out --------
__global__ __launch_bounds__(256) void k_prep(
    unsigned char* __restrict__ partial, uint* __restrict__ degree)
{
    const int g = blockIdx.x * 256 + threadIdx.x;   // node-group of 4
    if (g >= N_NODES / 4) return;
    uint r0 = 0, r1 = 0, r2 = 0, r3 = 0;
    for (int b = 0; b < HB; ++b) {
        uint* w = (uint*)(partial + (size_t)b * N_NODES) + g;
        const uint v = *w;
        *w = r0 | (r1 << 8) | (r2 << 16) | (r3 << 24);
        r0 += v & 0xffu; r1 += (v >> 8) & 0xffu; r2 += (v >> 16) & 0xffu; r3 += (v >> 24) & 0xffu;
    }
    ((uint4*)degree)[g] = make_uint4(r0, r1, r2, r3);
}

// ---------------- rowptr = exclusive scan of degree ----------------
__global__ __launch_bounds__(256) void k_scan1(
    const uint* __restrict__ degree, uint* __restrict__ rowptr, uint* __restrict__ bsum)
{
    __shared__ uint s[256];
    const int tid = threadIdx.x;
    const int g = blockIdx.x * 256 + tid;
    const uint v = (g < N_NODES) ? degree[g] : 0u;
    s[tid] = v; __syncthreads();
    for (int off = 1; off < 256; off <<= 1) {
        const uint t = (tid >= off) ? s[tid - off] : 0u;
        __syncthreads();
        s[tid] += t;
        __syncthreads();
    }
    if (g < N_NODES) rowptr[g] = s[tid] - v;
    if (tid == 255) bsum[blockIdx.x] = s[255];
}

__global__ __launch_bounds__(512) void k_scan2(uint* __restrict__ bsum)
{
    __shared__ uint s[512];
    const int tid = threadIdx.x;
    const uint v = (tid < NSCAN_B) ? bsum[tid] : 0u;
    s[tid] = v; __syncthreads();
    for (int off = 1; off < 512; off <<= 1) {
        const uint t = (tid >= off) ? s[tid - off] : 0u;
        __syncthreads();
        s[tid] += t;
        __syncthreads();
    }
    if (tid < NSCAN_B) bsum[tid] = s[tid] - v;
}

__global__ __launch_bounds__(256) void k_scan3(
    uint* __restrict__ rowptr, const uint* __restrict__ bsum)
{
    const int g = blockIdx.x * 256 + threadIdx.x;
    if (g < N_NODES) rowptr[g] += bsum[blockIdx.x];
    if (blockIdx.x == 0 && threadIdx.x == 0) rowptr[N_NODES] = N_EDGES;
}

// ---------------- CSR scatter: LDS-atomic local rank, plain global stores --
__global__ __launch_bounds__(256) void k_scatter(
    const int* __restrict__ esrc, const int* __restrict__ edst,
    const float* __restrict__ attr,
    const unsigned char* __restrict__ partial, const uint* __restrict__ rowptr,
    uint2* __restrict__ vals)
{
    __shared__ uint bins[HRANGE / 4];   // 25 KB, u8 running counters
    const int bx = blockIdx.x, p = blockIdx.y;
    const int base = p * HRANGE;
    for (int i = threadIdx.x; i < HRANGE / 4; i += 256) bins[i] = 0;
    __syncthreads();

    const unsigned char* pre = partial + (size_t)bx * N_NODES;
    const int e0 = bx * CHUNK, e1 = e0 + CHUNK;
    for (int e = e0 + threadIdx.x; e < e1; e += 256) {
        const int d = edst[e];
        const uint dr = (uint)(d - base);
        if (dr < HRANGE) {
            const uint sh  = (dr & 3) * 8;
            const uint old = atomicAdd(&bins[dr >> 2], 1u << sh);
            const uint local = (old >> sh) & 0xffu;
            const uint pos = rowptr[d] + (uint)pre[d] + local;
            vals[pos] = make_uint2((uint)esrc[e], __float_as_uint(attr[e]));
        }
    }
}

// ---------------- layer-1 pull aggregate + ELU + layer-2 transforms --------
// wave per node; lanes = 4 edge-groups x 16 features.
// CSR entries staged in LDS via ONE coalesced load + barrier (exec-mask safe,
// unlike shfl from divergently-exited lanes). unroll-4 puts 4 independent
// hp gathers in flight per group.
__global__ __launch_bounds__(256) void k_agg1(
    const uint* __restrict__ rowptr, const uint2* __restrict__ vals,
    const __half2* __restrict__ hp, const float* __restrict__ r1,
    const float* __restrict__ W2, const float* __restrict__ root2,
    const float* __restrict__ b2,
    float4* __restrict__ h2, float2* __restrict__ r2)
{
    __shared__ uint2 ent[4][64];        // 2 KB: per-wave CSR entry stage
    __shared__ float w2s[2 * F_HID * F_OUT];
    __shared__ float rts[F_HID * F_OUT];
    __shared__ float b2s[F_OUT];
    const int tid = threadIdx.x;
    if (tid < 2 * F_HID * F_OUT) w2s[tid] = W2[tid];
    if (tid < F_HID * F_OUT)     rts[tid] = root2[tid];
    if (tid < F_OUT)             b2s[tid] = b2[tid];

    const int lane = tid & 63;
    const int wave = tid >> 6;
    const int n = blockIdx.x * 4 + wave;
    const int ep = lane >> 4;          // 0..3
    const int c  = lane & 15;          // feature

    const uint r0 = rowptr[n];
    const uint deg = rowptr[n + 1] - r0;
    const uint dcap = min(deg, 64u);

    if ((uint)lane < dcap)
        ent[wave][lane] = vals[r0 + lane];   // one coalesced 8B/lane load
    __syncthreads();

    float acc = 0.f;
    #pragma unroll 4
    for (uint i = ep; i < dcap; i += 4) {
        const uint2 v = ent[wave][i];        // LDS broadcast, ~10 cyc
        const float uu = __uint_as_float(v.y);
        const float2 h = __half22float2(hp[(size_t)v.x * F_HID + c]);
        acc += (1.0f - uu) * h.x + uu * h.y;
    }
    for (uint i = 64 + ep; i < deg; i += 4) {    // rare overflow tail
        const uint2 v = vals[r0 + i];
        const float uu = __uint_as_float(v.y);
        const float2 h = __half22float2(hp[(size_t)v.x * F_HID + c]);
        acc += (1.0f - uu) * h.x + uu * h.y;
    }
    acc += __shfl_xor(acc, 16);
    acc += __shfl_xor(acc, 32);

    const float inv = 1.0f / (float)max(deg, 1u);
    const float vv = acc * inv + r1[(size_t)n * F_HID + c];
    const float hcf = (vv > 0.0f) ? vv : expm1f(vv);   // ELU

    float o00 = 0.f, o01 = 0.f, o10 = 0.f, o11 = 0.f;
    float rr0 = b2s[0], rr1 = b2s[1];
    #pragma unroll
    for (int f = 0; f < F_HID; ++f) {
        const float hv = __shfl(hcf, f);   // lanes 0..15 all active here
        o00 = fmaf(hv, w2s[f * 2 + 0], o00);
        o01 = fmaf(hv, w2s[f * 2 + 1], o01);
        o10 = fmaf(hv, w2s[2 * F_HID + f * 2 + 0], o10);
        o11 = fmaf(hv, w2s[2 * F_HID + f * 2 + 1], o11);
        rr0 = fmaf(hv, rts[f * 2 + 0], rr0);
        rr1 = fmaf(hv, rts[f * 2 + 1], rr1);
    }
    if (lane == 0) {
        h2[n] = make_float4(o00, o10, o01, o11);   // [feat0:(k0,k1), feat1:(k0,k1)]
        r2[n] = make_float2(rr0, rr1);
    }
}

// ---------------- layer-2 pull aggregate + log_softmax --------------------
// wave per node; lanes = 32 edge-groups x 2 features; LDS-staged entries.
__global__ __launch_bounds__(256) void k_agg2(
    const uint* __restrict__ rowptr, const uint2* __restrict__ vals,
    const float2* __restrict__ h2f2, const float2* __restrict__ r2,
    float* __restrict__ out)
{
    __shared__ uint2 ent[4][64];        // 2 KB
    const int tid = threadIdx.x;
    const int lane = tid & 63;
    const int wave = tid >> 6;
    const int n = blockIdx.x * 4 + wave;
    const int ep = lane >> 1;          // 0..31
    const int fp = lane & 1;           // feature

    const uint r0 = rowptr[n];
    const uint deg = rowptr[n + 1] - r0;
    const uint dcap = min(deg, 64u);

    if ((uint)lane < dcap)
        ent[wave][lane] = vals[r0 + lane];
    __syncthreads();

    float acc = 0.f;
    #pragma unroll 2
    for (uint i = ep; i < dcap; i += 32) {
        const uint2 v = ent[wave][i];
        const float uu = __uint_as_float(v.y);
        const float2 g = h2f2[(size_t)v.x * 2 + fp];
        acc += (1.0f - uu) * g.x + uu * g.y;
    }
    for (uint i = 64 + ep; i < deg; i += 32) {   // rare overflow tail
        const uint2 v = vals[r0 + i];
        const float uu = __uint_as_float(v.y);
        const float2 g = h2f2[(size_t)v.x * 2 + fp];
        acc += (1.0f - uu) * g.x + uu * g.y;
    }
    #pragma unroll
    for (int off = 2; off < 64; off <<= 1) acc += __shfl_xor(acc, off);

    const float inv = 1.0f / (float)max(deg, 1u);
    const float rv = fp ? r2[n].y : r2[n].x;
    const float o = acc * inv + rv;
    const float other = __shfl_xor(o, 1);
    const float m = fmaxf(o, other);
    const float l = m + logf(expf(o - m) + expf(other - m));
    if (lane < 2) out[(size_t)n * 2 + fp] = o - l;
}

extern "C" void kernel_launch(void* const* d_in, const int* in_sizes, int n_in,
                              void* d_out, int out_size, void* d_ws, size_t ws_size,
                              hipStream_t stream) {
    const float* x     = (const float*)d_in[0];
    const int*   ei    = (const int*)  d_in[1];   // [2][N_EDGES]
    const float* attr  = (const float*)d_in[2];
    const float* W1    = (const float*)d_in[4];
    const float* root1 = (const float*)d_in[5];
    const float* b1    = (const float*)d_in[6];
    const float* W2    = (const float*)d_in[7];
    const float* root2 = (const float*)d_in[8];
    const float* b2    = (const float*)d_in[9];
    float* out = (float*)d_out;

    char* ws = (char*)d_ws;
    size_t off = 0;
    uint2*   vals  = (uint2*)  (ws + off); off += (size_t)N_EDGES * sizeof(uint2);       // 25.6MB
    uint*    rowptr= (uint*)   (ws + off); off += (size_t)(N_NODES + 1) * sizeof(uint);
    uint*    degree= (uint*)   (ws + off); off += (size_t)N_NODES * sizeof(uint);
    uint*    bsum  = (uint*)   (ws + off); off += (size_t)512 * sizeof(uint);
    off = (off + 255) & ~(size_t)255;
    unsigned char* partial = (unsigned char*)(ws + off); off += (size_t)HB * N_NODES;    // 25.6MB

    // partial is dead after k_scatter; alias the node-transform buffers onto it
    // (stream-ordered: k_transform1 launches after k_scatter).
    char* alias = (char*)partial;
    size_t aoff = 0;
    __half2* hp = (__half2*)(alias + aoff); aoff += (size_t)N_NODES * F_HID * sizeof(__half2); // 6.4MB
    float*   r1 = (float*)  (alias + aoff); aoff += (size_t)N_NODES * F_HID * sizeof(float);   // 6.4MB
    float4*  h2 = (float4*) (alias + aoff); aoff += (size_t)N_NODES * sizeof(float4);          // 1.6MB
    float2*  r2 = (float2*) (alias + aoff); aoff += (size_t)N_NODES * sizeof(float2);          // 0.8MB

    const int* esrc = ei;
    const int* edst = ei + N_EDGES;

    k_hist     <<<dim3(HB, PASSES), 256, 0, stream>>>(edst, partial);
    k_prep     <<<(N_NODES / 4 + 255) / 256, 256, 0, stream>>>(partial, degree);
    k_scan1    <<<NSCAN_B, 256, 0, stream>>>(degree, rowptr, bsum);
    k_scan2    <<<1, 512, 0, stream>>>(bsum);
    k_scan3    <<<NSCAN_B, 256, 0, stream>>>(rowptr, bsum);
    k_scatter  <<<dim3(HB, PASSES), 256, 0, stream>>>(esrc, edst, attr, partial, rowptr, vals);
    k_transform1<<<(N_NODES + 127) / 128, 128, 0, stream>>>(x, W1, root1, b1, hp, r1);
    k_agg1     <<<N_NODES / 4, 256, 0, stream>>>(rowptr, vals, hp, r1, W2, root2, b2, h2, r2);
    k_agg2     <<<N_NODES / 4, 256, 0, stream>>>(rowptr, vals, (const float2*)h2, r2, out);
}

// Round 7
// 248.889 us; speedup vs baseline: 2.8457x; 1.1548x over previous
//
#include <hip/hip_runtime.h>
#include <hip/hip_fp16.h>

#define N_NODES 100000
#define N_EDGES 3200000
#define F_IN    61
#define F_HID   16
#define F_OUT   2
#define HB      256                    // edge chunks
#define CHUNK   (N_EDGES / HB)         // 12500
#define NBIN    (N_NODES / 4)          // 25000 packed-u8 words = 100 KB LDS
#define NSCAN_B 391                    // ceil(N_NODES/256)

typedef unsigned int uint;

// ---------------- layer-1 node transforms ----------------
// hp[n][c] = half2(h0[c], h1[c]);  r1[n][c] = (x @ root1 + b1)[c]  (f32)
__global__ __launch_bounds__(128) void k_transform1(
    const float* __restrict__ x, const float* __restrict__ W1,
    const float* __restrict__ root1, const float* __restrict__ b1,
    __half2* __restrict__ hp, float* __restrict__ r1)
{
    __shared__ float xs[128 * F_IN];
    __shared__ float w0s[F_IN * F_HID];
    __shared__ float w1s[F_IN * F_HID];
    __shared__ float rs [F_IN * F_HID];
    __shared__ float bs [F_HID];

    const int tid = threadIdx.x;
    for (int i = tid; i < F_IN * F_HID; i += 128) {
        w0s[i] = W1[i];
        w1s[i] = W1[F_IN * F_HID + i];
        rs[i]  = root1[i];
    }
    if (tid < F_HID) bs[tid] = b1[tid];

    const int n0 = blockIdx.x * 128;
    const int nodes = min(128, N_NODES - n0);
    for (int i = tid; i < nodes * F_IN; i += 128)
        xs[i] = x[(size_t)n0 * F_IN + i];
    __syncthreads();

    if (tid < nodes) {
        const int n = n0 + tid;
        float a0[F_HID], a1[F_HID], ar[F_HID];
        #pragma unroll
        for (int c = 0; c < F_HID; ++c) { a0[c] = 0.f; a1[c] = 0.f; ar[c] = 0.f; }
        const float* xr = &xs[tid * F_IN];
        for (int f = 0; f < F_IN; ++f) {
            const float xv = xr[f];
            #pragma unroll
            for (int c = 0; c < F_HID; ++c) {
                a0[c] = fmaf(xv, w0s[f * F_HID + c], a0[c]);
                a1[c] = fmaf(xv, w1s[f * F_HID + c], a1[c]);
                ar[c] = fmaf(xv, rs [f * F_HID + c], ar[c]);
            }
        }
        #pragma unroll
        for (int c = 0; c < F_HID; ++c) {
            hp[(size_t)n * F_HID + c] = __floats2half2_rn(a0[c], a1[c]);
            r1[(size_t)n * F_HID + c] = ar[c] + bs[c];
        }
    }
}

// ---------------- degree histogram: single pass, full-range u8 bins --------
// 100 KB LDS, one block per chunk; counts all dst of chunk bx.
__global__ __launch_bounds__(1024) void k_hist(
    const int* __restrict__ edst, unsigned char* __restrict__ partial)
{
    __shared__ uint bins[NBIN];         // 100 KB, u8 bins packed in u32
    const int bx = blockIdx.x;
    const int tid = threadIdx.x;
    for (int i = tid; i < NBIN; i += 1024) bins[i] = 0;
    __syncthreads();

    const int e0 = bx * CHUNK, e1 = e0 + CHUNK;
    for (int e = e0 + tid; e < e1; e += 1024) {
        const uint d = (uint)edst[e];
        atomicAdd(&bins[d >> 2], 1u << ((d & 3) * 8));   // chunk deg << 255
    }
    __syncthreads();

    uint* dp = (uint*)(partial + (size_t)bx * N_NODES);
    for (int i = tid; i < NBIN; i += 1024) dp[i] = bins[i];
}

// ---- per-(chunk,node) exclusive prefix over chunks; degree[n] out --------
__global__ __launch_bounds__(256) void k_prep(
    unsigned char* __restrict__ partial, uint* __restrict__ degree)
{
    const int g = blockIdx.x * 256 + threadIdx.x;   // node-group of 4
    if (g >= N_NODES / 4) return;
    uint r0 = 0, r1 = 0, r2 = 0, r3 = 0;
    for (int b = 0; b < HB; ++b) {
        uint* w = (uint*)(partial + (size_t)b * N_NODES) + g;
        const uint v = *w;
        *w = r0 | (r1 << 8) | (r2 << 16) | (r3 << 24);
        r0 += v & 0xffu; r1 += (v >> 8) & 0xffu; r2 += (v >> 16) & 0xffu; r3 += (v >> 24) & 0xffu;
    }
    ((uint4*)degree)[g] = make_uint4(r0, r1, r2, r3);
}

// ---------------- rowptr = exclusive scan of degree ----------------
__global__ __launch_bounds__(256) void k_scan1(
    const uint* __restrict__ degree, uint* __restrict__ rowptr, uint* __restrict__ bsum)
{
    __shared__ uint s[256];
    const int tid = threadIdx.x;
    const int g = blockIdx.x * 256 + tid;
    const uint v = (g < N_NODES) ? degree[g] : 0u;
    s[tid] = v; __syncthreads();
    for (int off = 1; off < 256; off <<= 1) {
        const uint t = (tid >= off) ? s[tid - off] : 0u;
        __syncthreads();
        s[tid] += t;
        __syncthreads();
    }
    if (g < N_NODES) rowptr[g] = s[tid] - v;
    if (tid == 255) bsum[blockIdx.x] = s[255];
}

__global__ __launch_bounds__(512) void k_scan2(uint* __restrict__ bsum)
{
    __shared__ uint s[512];
    const int tid = threadIdx.x;
    const uint v = (tid < NSCAN_B) ? bsum[tid] : 0u;
    s[tid] = v; __syncthreads();
    for (int off = 1; off < 512; off <<= 1) {
        const uint t = (tid >= off) ? s[tid - off] : 0u;
        __syncthreads();
        s[tid] += t;
        __syncthreads();
    }
    if (tid < NSCAN_B) bsum[tid] = s[tid] - v;
}

__global__ __launch_bounds__(256) void k_scan3(
    uint* __restrict__ rowptr, const uint* __restrict__ bsum)
{
    const int g = blockIdx.x * 256 + threadIdx.x;
    if (g < N_NODES) rowptr[g] += bsum[blockIdx.x];
    if (blockIdx.x == 0 && threadIdx.x == 0) rowptr[N_NODES] = N_EDGES;
}

// ---------------- CSR scatter: single pass, bins seeded with prefix --------
// LDS counters initialized to the per-(chunk,node) exclusive prefix via one
// coalesced 100 KB read -> atomicAdd returns (prefix+local) directly. Only
// remaining per-edge random read is rowptr[d] (400 KB, L2-resident).
__global__ __launch_bounds__(1024) void k_scatter(
    const int* __restrict__ esrc, const int* __restrict__ edst,
    const float* __restrict__ attr,
    const unsigned char* __restrict__ partial, const uint* __restrict__ rowptr,
    uint2* __restrict__ vals)
{
    __shared__ uint bins[NBIN];         // 100 KB, u8 running counters
    const int bx = blockIdx.x;
    const int tid = threadIdx.x;
    const uint* prow = (const uint*)(partial + (size_t)bx * N_NODES);
    for (int i = tid; i < NBIN; i += 1024) bins[i] = prow[i];   // coalesced seed
    __syncthreads();

    const int e0 = bx * CHUNK, e1 = e0 + CHUNK;
    for (int e = e0 + tid; e < e1; e += 1024) {
        const uint d  = (uint)edst[e];
        const uint sh = (d & 3) * 8;
        const uint old = atomicAdd(&bins[d >> 2], 1u << sh);
        const uint pos = rowptr[d] + ((old >> sh) & 0xffu);
        vals[pos] = make_uint2((uint)esrc[e], __float_as_uint(attr[e]));
    }
}

// ---------------- layer-1 pull aggregate + ELU + layer-2 transforms --------
// wave per node; lanes = 4 edge-groups x 16 features.
// CSR entries staged in LDS via ONE coalesced load + barrier (exec-mask safe).
__global__ __launch_bounds__(256) void k_agg1(
    const uint* __restrict__ rowptr, const uint2* __restrict__ vals,
    const __half2* __restrict__ hp, const float* __restrict__ r1,
    const float* __restrict__ W2, const float* __restrict__ root2,
    const float* __restrict__ b2,
    float4* __restrict__ h2, float2* __restrict__ r2)
{
    __shared__ uint2 ent[4][64];        // 2 KB: per-wave CSR entry stage
    __shared__ float w2s[2 * F_HID * F_OUT];
    __shared__ float rts[F_HID * F_OUT];
    __shared__ float b2s[F_OUT];
    const int tid = threadIdx.x;
    if (tid < 2 * F_HID * F_OUT) w2s[tid] = W2[tid];
    if (tid < F_HID * F_OUT)     rts[tid] = root2[tid];
    if (tid < F_OUT)             b2s[tid] = b2[tid];

    const int lane = tid & 63;
    const int wave = tid >> 6;
    const int n = blockIdx.x * 4 + wave;
    const int ep = lane >> 4;          // 0..3
    const int c  = lane & 15;          // feature

    const uint r0 = rowptr[n];
    const uint deg = rowptr[n + 1] - r0;
    const uint dcap = min(deg, 64u);

    if ((uint)lane < dcap)
        ent[wave][lane] = vals[r0 + lane];   // one coalesced 8B/lane load
    __syncthreads();

    float acc = 0.f;
    #pragma unroll 4
    for (uint i = ep; i < dcap; i += 4) {
        const uint2 v = ent[wave][i];        // LDS broadcast
        const float uu = __uint_as_float(v.y);
        const float2 h = __half22float2(hp[(size_t)v.x * F_HID + c]);
        acc += (1.0f - uu) * h.x + uu * h.y;
    }
    for (uint i = 64 + ep; i < deg; i += 4) {    // rare overflow tail
        const uint2 v = vals[r0 + i];
        const float uu = __uint_as_float(v.y);
        const float2 h = __half22float2(hp[(size_t)v.x * F_HID + c]);
        acc += (1.0f - uu) * h.x + uu * h.y;
    }
    acc += __shfl_xor(acc, 16);
    acc += __shfl_xor(acc, 32);

    const float inv = 1.0f / (float)max(deg, 1u);
    const float vv = acc * inv + r1[(size_t)n * F_HID + c];
    const float hcf = (vv > 0.0f) ? vv : expm1f(vv);   // ELU

    float o00 = 0.f, o01 = 0.f, o10 = 0.f, o11 = 0.f;
    float rr0 = b2s[0], rr1 = b2s[1];
    #pragma unroll
    for (int f = 0; f < F_HID; ++f) {
        const float hv = __shfl(hcf, f);   // lanes 0..15 all active here
        o00 = fmaf(hv, w2s[f * 2 + 0], o00);
        o01 = fmaf(hv, w2s[f * 2 + 1], o01);
        o10 = fmaf(hv, w2s[2 * F_HID + f * 2 + 0], o10);
        o11 = fmaf(hv, w2s[2 * F_HID + f * 2 + 1], o11);
        rr0 = fmaf(hv, rts[f * 2 + 0], rr0);
        rr1 = fmaf(hv, rts[f * 2 + 1], rr1);
    }
    if (lane == 0) {
        h2[n] = make_float4(o00, o10, o01, o11);   // [feat0:(k0,k1), feat1:(k0,k1)]
        r2[n] = make_float2(rr0, rr1);
    }
}

// ---------------- layer-2 pull aggregate + log_softmax --------------------
// wave per node; lanes = 32 edge-groups x 2 features; LDS-staged entries.
__global__ __launch_bounds__(256) void k_agg2(
    const uint* __restrict__ rowptr, const uint2* __restrict__ vals,
    const float2* __restrict__ h2f2, const float2* __restrict__ r2,
    float* __restrict__ out)
{
    __shared__ uint2 ent[4][64];        // 2 KB
    const int tid = threadIdx.x;
    const int lane = tid & 63;
    const int wave = tid >> 6;
    const int n = blockIdx.x * 4 + wave;
    const int ep = lane >> 1;          // 0..31
    const int fp = lane & 1;           // feature

    const uint r0 = rowptr[n];
    const uint deg = rowptr[n + 1] - r0;
    const uint dcap = min(deg, 64u);

    if ((uint)lane < dcap)
        ent[wave][lane] = vals[r0 + lane];
    __syncthreads();

    float acc = 0.f;
    #pragma unroll 2
    for (uint i = ep; i < dcap; i += 32) {
        const uint2 v = ent[wave][i];
        const float uu = __uint_as_float(v.y);
        const float2 g = h2f2[(size_t)v.x * 2 + fp];
        acc += (1.0f - uu) * g.x + uu * g.y;
    }
    for (uint i = 64 + ep; i < deg; i += 32) {   // rare overflow tail
        const uint2 v = vals[r0 + i];
        const float uu = __uint_as_float(v.y);
        const float2 g = h2f2[(size_t)v.x * 2 + fp];
        acc += (1.0f - uu) * g.x + uu * g.y;
    }
    #pragma unroll
    for (int off = 2; off < 64; off <<= 1) acc += __shfl_xor(acc, off);

    const float inv = 1.0f / (float)max(deg, 1u);
    const float rv = fp ? r2[n].y : r2[n].x;
    const float o = acc * inv + rv;
    const float other = __shfl_xor(o, 1);
    const float m = fmaxf(o, other);
    const float l = m + logf(expf(o - m) + expf(other - m));
    if (lane < 2) out[(size_t)n * 2 + fp] = o - l;
}

extern "C" void kernel_launch(void* const* d_in, const int* in_sizes, int n_in,
                              void* d_out, int out_size, void* d_ws, size_t ws_size,
                              hipStream_t stream) {
    const float* x     = (const float*)d_in[0];
    const int*   ei    = (const int*)  d_in[1];   // [2][N_EDGES]
    const float* attr  = (const float*)d_in[2];
    const float* W1    = (const float*)d_in[4];
    const float* root1 = (const float*)d_in[5];
    const float* b1    = (const float*)d_in[6];
    const float* W2    = (const float*)d_in[7];
    const float* root2 = (const float*)d_in[8];
    const float* b2    = (const float*)d_in[9];
    float* out = (float*)d_out;

    char* ws = (char*)d_ws;
    size_t off = 0;
    uint2*   vals  = (uint2*)  (ws + off); off += (size_t)N_EDGES * sizeof(uint2);       // 25.6MB
    uint*    rowptr= (uint*)   (ws + off); off += (size_t)(N_NODES + 1) * sizeof(uint);
    uint*    degree= (uint*)   (ws + off); off += (size_t)N_NODES * sizeof(uint);
    uint*    bsum  = (uint*)   (ws + off); off += (size_t)512 * sizeof(uint);
    off = (off + 255) & ~(size_t)255;
    unsigned char* partial = (unsigned char*)(ws + off); off += (size_t)HB * N_NODES;    // 25.6MB

    // partial is dead after k_scatter; alias the node-transform buffers onto it
    // (stream-ordered: k_transform1 launches after k_scatter).
    char* alias = (char*)partial;
    size_t aoff = 0;
    __half2* hp = (__half2*)(alias + aoff); aoff += (size_t)N_NODES * F_HID * sizeof(__half2); // 6.4MB
    float*   r1 = (float*)  (alias + aoff); aoff += (size_t)N_NODES * F_HID * sizeof(float);   // 6.4MB
    float4*  h2 = (float4*) (alias + aoff); aoff += (size_t)N_NODES * sizeof(float4);          // 1.6MB
    float2*  r2 = (float2*) (alias + aoff); aoff += (size_t)N_NODES * sizeof(float2);          // 0.8MB

    const int* esrc = ei;
    const int* edst = ei + N_EDGES;

    k_hist     <<<HB, 1024, 0, stream>>>(edst, partial);
    k_prep     <<<(N_NODES / 4 + 255) / 256, 256, 0, stream>>>(partial, degree);
    k_scan1    <<<NSCAN_B, 256, 0, stream>>>(degree, rowptr, bsum);
    k_scan2    <<<1, 512, 0, stream>>>(bsum);
    k_scan3    <<<NSCAN_B, 256, 0, stream>>>(rowptr, bsum);
    k_scatter  <<<HB, 1024, 0, stream>>>(esrc, edst, attr, partial, rowptr, vals);
    k_transform1<<<(N_NODES + 127) / 128, 128, 0, stream>>>(x, W1, root1, b1, hp, r1);
    k_agg1     <<<N_NODES / 4, 256, 0, stream>>>(rowptr, vals, hp, r1, W2, root2, b2, h2, r2);
    k_agg2     <<<N_NODES / 4, 256, 0, stream>>>(rowptr, vals, (const float2*)h2, r2, out);
}

// Round 8
// 235.556 us; speedup vs baseline: 3.0068x; 1.0566x over previous
//
#include <hip/hip_runtime.h>
#include <hip/hip_fp16.h>

#define N_NODES 100000
#define N_EDGES 3200000
#define F_IN    61
#define F_HID   16
#define F_OUT   2
#define HB      256                    // edge chunks
#define CHUNK   (N_EDGES / HB)         // 12500
#define BSIZE   512                    // nodes per dst-bucket
#define NBUCK   196                    // ceil(N_NODES / BSIZE)

typedef unsigned int uint;

// ---------------- layer-1 node transforms ----------------
// hp[n][c] = half2(h0[c], h1[c]);  r1[n][c] = (x @ root1 + b1)[c]  (f32)
__global__ __launch_bounds__(128) void k_transform1(
    const float* __restrict__ x, const float* __restrict__ W1,
    const float* __restrict__ root1, const float* __restrict__ b1,
    __half2* __restrict__ hp, float* __restrict__ r1)
{
    __shared__ float xs[128 * F_IN];
    __shared__ float w0s[F_IN * F_HID];
    __shared__ float w1s[F_IN * F_HID];
    __shared__ float rs [F_IN * F_HID];
    __shared__ float bs [F_HID];

    const int tid = threadIdx.x;
    for (int i = tid; i < F_IN * F_HID; i += 128) {
        w0s[i] = W1[i];
        w1s[i] = W1[F_IN * F_HID + i];
        rs[i]  = root1[i];
    }
    if (tid < F_HID) bs[tid] = b1[tid];

    const int n0 = blockIdx.x * 128;
    const int nodes = min(128, N_NODES - n0);
    for (int i = tid; i < nodes * F_IN; i += 128)
        xs[i] = x[(size_t)n0 * F_IN + i];
    __syncthreads();

    if (tid < nodes) {
        const int n = n0 + tid;
        float a0[F_HID], a1[F_HID], ar[F_HID];
        #pragma unroll
        for (int c = 0; c < F_HID; ++c) { a0[c] = 0.f; a1[c] = 0.f; ar[c] = 0.f; }
        const float* xr = &xs[tid * F_IN];
        for (int f = 0; f < F_IN; ++f) {
            const float xv = xr[f];
            #pragma unroll
            for (int c = 0; c < F_HID; ++c) {
                a0[c] = fmaf(xv, w0s[f * F_HID + c], a0[c]);
                a1[c] = fmaf(xv, w1s[f * F_HID + c], a1[c]);
                ar[c] = fmaf(xv, rs [f * F_HID + c], ar[c]);
            }
        }
        #pragma unroll
        for (int c = 0; c < F_HID; ++c) {
            hp[(size_t)n * F_HID + c] = __floats2half2_rn(a0[c], a1[c]);
            r1[(size_t)n * F_HID + c] = ar[c] + bs[c];
        }
    }
}

// ---------------- phase A: per-(chunk,bucket) counts ----------------
// cnt laid out [bucket][chunk] so k_bscan streams rows.
__global__ __launch_bounds__(1024) void k_bhist(
    const int* __restrict__ edst, uint* __restrict__ cnt)
{
    __shared__ uint bins[NBUCK];
    const int bx = blockIdx.x, tid = threadIdx.x;
    for (int i = tid; i < NBUCK; i += 1024) bins[i] = 0;
    __syncthreads();
    const int e0 = bx * CHUNK, e1 = e0 + CHUNK;
    for (int e = e0 + tid; e < e1; e += 1024)
        atomicAdd(&bins[((uint)edst[e]) >> 9], 1u);
    __syncthreads();
    for (int i = tid; i < NBUCK; i += 1024) cnt[(size_t)i * HB + bx] = bins[i];
}

// ---- bucket totals + two-level exclusive scan; cnt becomes seg offsets ----
__global__ __launch_bounds__(256) void k_bscan(
    uint* __restrict__ cnt, uint* __restrict__ bstart)
{
    __shared__ uint tot[256];
    const int b = threadIdx.x;
    uint sum = 0;
    if (b < NBUCK) {
        const uint* row = cnt + (size_t)b * HB;
        for (int c = 0; c < HB; ++c) sum += row[c];
    }
    tot[b] = sum; __syncthreads();
    for (int off = 1; off < 256; off <<= 1) {
        const uint t = (b >= off) ? tot[b - off] : 0u;
        __syncthreads();
        tot[b] += t;
        __syncthreads();
    }
    const uint base = tot[b] - sum;     // exclusive over buckets
    if (b < NBUCK) {
        bstart[b] = base;
        uint run = base;
        uint* row = cnt + (size_t)b * HB;
        for (int c = 0; c < HB; ++c) { const uint t = row[c]; row[c] = run; run += t; }
    }
    if (b == 0) bstart[NBUCK] = N_EDGES;
}

// ---- phase A scatter: append each edge to its bucket stream --------------
// Writes land in ~100 KB/block active windows -> L2-merged dense sectors.
__global__ __launch_bounds__(1024) void k_bscatter(
    const int* __restrict__ esrc, const int* __restrict__ edst,
    const float* __restrict__ attr, const uint* __restrict__ cnt,
    uint2* __restrict__ buck)
{
    __shared__ uint pos[NBUCK];
    const int bx = blockIdx.x, tid = threadIdx.x;
    for (int i = tid; i < NBUCK; i += 1024) pos[i] = cnt[(size_t)i * HB + bx];
    __syncthreads();
    const int e0 = bx * CHUNK, e1 = e0 + CHUNK;
    for (int e = e0 + tid; e < e1; e += 1024) {
        const uint d = (uint)edst[e];
        const uint p = atomicAdd(&pos[d >> 9], 1u);
        buck[p] = make_uint2((uint)esrc[e] | ((d & 511u) << 17),
                             __float_as_uint(attr[e]));
    }
}

// ---- phase B: per-bucket local count+scan -> rowptr, then dense scatter ---
__global__ __launch_bounds__(1024) void k_fscatter(
    const uint2* __restrict__ buck, const uint* __restrict__ bstart,
    uint* __restrict__ rowptr, uint2* __restrict__ vals)
{
    __shared__ uint deg[BSIZE];     // then running positions
    __shared__ uint excl[BSIZE];
    const int b = blockIdx.x, tid = threadIdx.x;
    const uint e0 = bstart[b], e1 = bstart[b + 1];

    for (int i = tid; i < BSIZE; i += 1024) deg[i] = 0;
    __syncthreads();
    for (uint e = e0 + tid; e < e1; e += 1024)
        atomicAdd(&deg[(buck[e].x >> 17) & 511u], 1u);
    __syncthreads();

    if (tid < BSIZE) excl[tid] = deg[tid];
    __syncthreads();
    for (int off = 1; off < BSIZE; off <<= 1) {
        uint t = 0;
        if (tid < BSIZE && tid >= off) t = excl[tid - off];
        __syncthreads();
        if (tid < BSIZE) excl[tid] += t;
        __syncthreads();
    }
    if (tid < BSIZE) {
        const uint ex = excl[tid] - deg[tid];   // exclusive prefix
        const int n = b * BSIZE + tid;
        if (n < N_NODES) rowptr[n] = e0 + ex;
        deg[tid] = ex;                          // reuse as running position
    }
    if (b == 0 && tid == 0) rowptr[N_NODES] = N_EDGES;
    __syncthreads();

    for (uint e = e0 + tid; e < e1; e += 1024) {
        const uint2 w = buck[e];
        const uint dl = (w.x >> 17) & 511u;
        const uint p = atomicAdd(&deg[dl], 1u);
        vals[e0 + p] = make_uint2(w.x & 0x1FFFFu, w.y);
    }
}

// ---------------- layer-1 pull aggregate + ELU + layer-2 transforms --------
// wave per node; lanes = 4 edge-groups x 16 features.
// CSR entries staged in LDS via ONE coalesced load + barrier (exec-mask safe).
__global__ __launch_bounds__(256) void k_agg1(
    const uint* __restrict__ rowptr, const uint2* __restrict__ vals,
    const __half2* __restrict__ hp, const float* __restrict__ r1,
    const float* __restrict__ W2, const float* __restrict__ root2,
    const float* __restrict__ b2,
    float4* __restrict__ h2, float2* __restrict__ r2)
{
    __shared__ uint2 ent[4][64];        // 2 KB: per-wave CSR entry stage
    __shared__ float w2s[2 * F_HID * F_OUT];
    __shared__ float rts[F_HID * F_OUT];
    __shared__ float b2s[F_OUT];
    const int tid = threadIdx.x;
    if (tid < 2 * F_HID * F_OUT) w2s[tid] = W2[tid];
    if (tid < F_HID * F_OUT)     rts[tid] = root2[tid];
    if (tid < F_OUT)             b2s[tid] = b2[tid];

    const int lane = tid & 63;
    const int wave = tid >> 6;
    const int n = blockIdx.x * 4 + wave;
    const int ep = lane >> 4;          // 0..3
    const int c  = lane & 15;          // feature

    const uint r0 = rowptr[n];
    const uint deg = rowptr[n + 1] - r0;
    const uint dcap = min(deg, 64u);

    if ((uint)lane < dcap)
        ent[wave][lane] = vals[r0 + lane];   // one coalesced 8B/lane load
    __syncthreads();

    float acc = 0.f;
    #pragma unroll 4
    for (uint i = ep; i < dcap; i += 4) {
        const uint2 v = ent[wave][i];        // LDS broadcast
        const float uu = __uint_as_float(v.y);
        const float2 h = __half22float2(hp[(size_t)v.x * F_HID + c]);
        acc += (1.0f - uu) * h.x + uu * h.y;
    }
    for (uint i = 64 + ep; i < deg; i += 4) {    // rare overflow tail
        const uint2 v = vals[r0 + i];
        const float uu = __uint_as_float(v.y);
        const float2 h = __half22float2(hp[(size_t)v.x * F_HID + c]);
        acc += (1.0f - uu) * h.x + uu * h.y;
    }
    acc += __shfl_xor(acc, 16);
    acc += __shfl_xor(acc, 32);

    const float inv = 1.0f / (float)max(deg, 1u);
    const float vv = acc * inv + r1[(size_t)n * F_HID + c];
    const float hcf = (vv > 0.0f) ? vv : expm1f(vv);   // ELU

    float o00 = 0.f, o01 = 0.f, o10 = 0.f, o11 = 0.f;
    float rr0 = b2s[0], rr1 = b2s[1];
    #pragma unroll
    for (int f = 0; f < F_HID; ++f) {
        const float hv = __shfl(hcf, f);   // lanes 0..15 all active here
        o00 = fmaf(hv, w2s[f * 2 + 0], o00);
        o01 = fmaf(hv, w2s[f * 2 + 1], o01);
        o10 = fmaf(hv, w2s[2 * F_HID + f * 2 + 0], o10);
        o11 = fmaf(hv, w2s[2 * F_HID + f * 2 + 1], o11);
        rr0 = fmaf(hv, rts[f * 2 + 0], rr0);
        rr1 = fmaf(hv, rts[f * 2 + 1], rr1);
    }
    if (lane == 0) {
        h2[n] = make_float4(o00, o10, o01, o11);   // [feat0:(k0,k1), feat1:(k0,k1)]
        r2[n] = make_float2(rr0, rr1);
    }
}

// ---------------- layer-2 pull aggregate + log_softmax --------------------
// wave per node; lanes = 32 edge-groups x 2 features; LDS-staged entries.
__global__ __launch_bounds__(256) void k_agg2(
    const uint* __restrict__ rowptr, const uint2* __restrict__ vals,
    const float2* __restrict__ h2f2, const float2* __restrict__ r2,
    float* __restrict__ out)
{
    __shared__ uint2 ent[4][64];        // 2 KB
    const int tid = threadIdx.x;
    const int lane = tid & 63;
    const int wave = tid >> 6;
    const int n = blockIdx.x * 4 + wave;
    const int ep = lane >> 1;          // 0..31
    const int fp = lane & 1;           // feature

    const uint r0 = rowptr[n];
    const uint deg = rowptr[n + 1] - r0;
    const uint dcap = min(deg, 64u);

    if ((uint)lane < dcap)
        ent[wave][lane] = vals[r0 + lane];
    __syncthreads();

    float acc = 0.f;
    #pragma unroll 2
    for (uint i = ep; i < dcap; i += 32) {
        const uint2 v = ent[wave][i];
        const float uu = __uint_as_float(v.y);
        const float2 g = h2f2[(size_t)v.x * 2 + fp];
        acc += (1.0f - uu) * g.x + uu * g.y;
    }
    for (uint i = 64 + ep; i < deg; i += 32) {   // rare overflow tail
        const uint2 v = vals[r0 + i];
        const float uu = __uint_as_float(v.y);
        const float2 g = h2f2[(size_t)v.x * 2 + fp];
        acc += (1.0f - uu) * g.x + uu * g.y;
    }
    #pragma unroll
    for (int off = 2; off < 64; off <<= 1) acc += __shfl_xor(acc, off);

    const float inv = 1.0f / (float)max(deg, 1u);
    const float rv = fp ? r2[n].y : r2[n].x;
    const float o = acc * inv + rv;
    const float other = __shfl_xor(o, 1);
    const float m = fmaxf(o, other);
    const float l = m + logf(expf(o - m) + expf(other - m));
    if (lane < 2) out[(size_t)n * 2 + fp] = o - l;
}

extern "C" void kernel_launch(void* const* d_in, const int* in_sizes, int n_in,
                              void* d_out, int out_size, void* d_ws, size_t ws_size,
                              hipStream_t stream) {
    const float* x     = (const float*)d_in[0];
    const int*   ei    = (const int*)  d_in[1];   // [2][N_EDGES]
    const float* attr  = (const float*)d_in[2];
    const float* W1    = (const float*)d_in[4];
    const float* root1 = (const float*)d_in[5];
    const float* b1    = (const float*)d_in[6];
    const float* W2    = (const float*)d_in[7];
    const float* root2 = (const float*)d_in[8];
    const float* b2    = (const float*)d_in[9];
    float* out = (float*)d_out;

    char* ws = (char*)d_ws;
    size_t off = 0;
    uint2* vals   = (uint2*)(ws + off); off += (size_t)N_EDGES * sizeof(uint2);        // 25.6MB
    uint*  rowptr = (uint*) (ws + off); off += (size_t)(N_NODES + 1) * sizeof(uint);
    uint*  cnt    = (uint*) (ws + off); off += (size_t)NBUCK * HB * sizeof(uint);      // 200KB
    uint*  bstart = (uint*) (ws + off); off += (size_t)(NBUCK + 1) * sizeof(uint);
    off = (off + 255) & ~(size_t)255;
    uint2* buck   = (uint2*)(ws + off); off += (size_t)N_EDGES * sizeof(uint2);        // 25.6MB

    // buck is dead after k_fscatter; alias the node buffers onto it
    // (stream-ordered: k_transform1 launches after k_fscatter).
    char* alias = (char*)buck;
    size_t aoff = 0;
    __half2* hp = (__half2*)(alias + aoff); aoff += (size_t)N_NODES * F_HID * sizeof(__half2); // 6.4MB
    float*   r1 = (float*)  (alias + aoff); aoff += (size_t)N_NODES * F_HID * sizeof(float);   // 6.4MB
    float4*  h2 = (float4*) (alias + aoff); aoff += (size_t)N_NODES * sizeof(float4);          // 1.6MB
    float2*  r2 = (float2*) (alias + aoff); aoff += (size_t)N_NODES * sizeof(float2);          // 0.8MB

    const int* esrc = ei;
    const int* edst = ei + N_EDGES;

    k_bhist    <<<HB, 1024, 0, stream>>>(edst, cnt);
    k_bscan    <<<1, 256, 0, stream>>>(cnt, bstart);
    k_bscatter <<<HB, 1024, 0, stream>>>(esrc, edst, attr, cnt, buck);
    k_fscatter <<<NBUCK, 1024, 0, stream>>>(buck, bstart, rowptr, vals);
    k_transform1<<<(N_NODES + 127) / 128, 128, 0, stream>>>(x, W1, root1, b1, hp, r1);
    k_agg1     <<<N_NODES / 4, 256, 0, stream>>>(rowptr, vals, hp, r1, W2, root2, b2, h2, r2);
    k_agg2     <<<N_NODES / 4, 256, 0, stream>>>(rowptr, vals, (const float2*)h2, r2, out);
}